// Round 2
// baseline (2251.142 us; speedup 1.0000x reference)
//
#include <hip/hip_runtime.h>
#include <hip/hip_bf16.h>
#include <math.h>

#define NNODES 100000
#define NEDGES 3200000
#define BN_EPS 1e-5f
#define NCH 391   // ceil(NNODES/256)

// ---------------- CSR build ----------------
// NOTE: harness passes integer inputs as int32 (edge_index: 2 x E int32).

__global__ void k_hist(const int* __restrict__ dst, int* __restrict__ cnt) {
    int e = blockIdx.x * 256 + threadIdx.x;
    if (e < NEDGES) atomicAdd(&cnt[dst[e]], 1);
}

__global__ void k_dinv(const int* __restrict__ cnt, float* __restrict__ dinv) {
    int i = blockIdx.x * 256 + threadIdx.x;
    if (i < NNODES) dinv[i] = rsqrtf((float)cnt[i] + 1.0f);  // deg includes self-loop
}

__global__ void k_chunksum(const int* __restrict__ cnt, int* __restrict__ chunksums) {
    __shared__ int s[256];
    int i = blockIdx.x * 256 + threadIdx.x;
    s[threadIdx.x] = (i < NNODES) ? cnt[i] : 0;
    __syncthreads();
    for (int o = 128; o > 0; o >>= 1) {
        if (threadIdx.x < o) s[threadIdx.x] += s[threadIdx.x + o];
        __syncthreads();
    }
    if (threadIdx.x == 0) chunksums[blockIdx.x] = s[0];
}

__global__ void k_scan1(int* __restrict__ chunksums, int* __restrict__ rowstart) {
    if (threadIdx.x == 0 && blockIdx.x == 0) {
        int run = 0;
        for (int i = 0; i < NCH; ++i) { int v = chunksums[i]; chunksums[i] = run; run += v; }
        rowstart[NNODES] = run;   // == NEDGES
    }
}

__global__ void k_scan2(const int* __restrict__ cnt, const int* __restrict__ chunkbase,
                        int* __restrict__ rowstart, int* __restrict__ cursor) {
    __shared__ int s[256];
    int t = threadIdx.x;
    int i = blockIdx.x * 256 + t;
    int v = (i < NNODES) ? cnt[i] : 0;
    s[t] = v;
    __syncthreads();
    for (int o = 1; o < 256; o <<= 1) {
        int add = (t >= o) ? s[t - o] : 0;
        __syncthreads();
        s[t] += add;
        __syncthreads();
    }
    if (i < NNODES) {
        int excl = s[t] - v + chunkbase[blockIdx.x];
        rowstart[i] = excl;
        cursor[i]   = excl;
    }
}

__global__ void k_scatter(const int* __restrict__ src, const int* __restrict__ dst,
                          const float* __restrict__ dinv, int* __restrict__ cursor,
                          int2* __restrict__ pairs) {
    int e = blockIdx.x * 256 + threadIdx.x;
    if (e >= NEDGES) return;
    int s = src[e], d = dst[e];
    int p = atomicAdd(&cursor[d], 1);
    float w = dinv[s] * dinv[d];
    pairs[p] = make_int2(s, __float_as_int(w));
}

// ---------------- aggregation: Y[d] = sum_e w_e * X[col_e] + dinv[d]^2 * X[d] (+bias) ----------------

template <int F>
__global__ void k_agg(const float* __restrict__ X, float* __restrict__ Y,
                      const int2* __restrict__ pairs, const int* __restrict__ rowstart,
                      const float* __restrict__ dinv, const float* __restrict__ bias) {
    const int d = blockIdx.x;
    const int t = threadIdx.x;   // F threads
    const int r0 = rowstart[d], r1 = rowstart[d + 1];
    float acc = 0.f;
    for (int p = r0; p < r1; ++p) {
        int2 pr = pairs[p];
        acc = fmaf(__int_as_float(pr.y), X[(size_t)pr.x * F + t], acc);
    }
    float di = dinv[d];
    acc = fmaf(di * di, X[(size_t)d * F + t], acc);
    if (bias) acc += bias[t];
    Y[(size_t)d * F + t] = acc;
}

// 40-wide aggregation: one wave per node, lanes 0..39
__global__ void k_agg40(const float* __restrict__ X, float* __restrict__ Y,
                        const int2* __restrict__ pairs, const int* __restrict__ rowstart,
                        const float* __restrict__ dinv, const float* __restrict__ bias) {
    int t = threadIdx.x;
    int w = t >> 6, lane = t & 63;
    int d = blockIdx.x * 4 + w;
    if (d >= NNODES || lane >= 40) return;
    const int r0 = rowstart[d], r1 = rowstart[d + 1];
    float acc = 0.f;
    for (int p = r0; p < r1; ++p) {
        int2 pr = pairs[p];
        acc = fmaf(__int_as_float(pr.y), X[(size_t)pr.x * 40 + lane], acc);
    }
    float di = dinv[d];
    acc = fmaf(di * di, X[(size_t)d * 40 + lane], acc);
    acc += bias[lane];
    Y[(size_t)d * 40 + lane] = acc;
}

// ---------------- GEMM: C[M x 256] = A[M x K] @ W[K x 256] (+bias) ----------------

template <int K>
__global__ __launch_bounds__(256) void k_gemm64(
    const float* __restrict__ A, const float* __restrict__ W,
    const float* __restrict__ bias, float* __restrict__ C) {
    __shared__ __align__(16) float As[32][68];  // [kk][row]
    __shared__ __align__(16) float Ws[32][68];  // [kk][col]
    const int m0 = blockIdx.x * 64;
    const int n0 = blockIdx.y * 64;
    const int tid = threadIdx.x;
    const int tx = tid & 15, ty = tid >> 4;
    const int kk_a = tid & 31, rg = tid >> 5;  // A-load role
    const int kk_w = tid >> 3, cq = tid & 7;   // W-load role
    float acc[4][4] = {};
    for (int k0 = 0; k0 < K; k0 += 32) {
#pragma unroll
        for (int j = 0; j < 8; ++j) {
            int m = m0 + rg * 8 + j;
            As[kk_a][rg * 8 + j] = (m < NNODES) ? A[(size_t)m * K + k0 + kk_a] : 0.f;
        }
        {
            const float* srcp = &W[(size_t)(k0 + kk_w) * 256 + n0 + cq * 8];
            *(float4*)&Ws[kk_w][cq * 8]     = *(const float4*)srcp;
            *(float4*)&Ws[kk_w][cq * 8 + 4] = *(const float4*)(srcp + 4);
        }
        __syncthreads();
#pragma unroll
        for (int kk = 0; kk < 32; ++kk) {
            float ar[4], br[4];
            *(float4*)ar = *(const float4*)&As[kk][ty * 4];
            *(float4*)br = *(const float4*)&Ws[kk][tx * 4];
#pragma unroll
            for (int i = 0; i < 4; ++i)
#pragma unroll
                for (int j = 0; j < 4; ++j)
                    acc[i][j] = fmaf(ar[i], br[j], acc[i][j]);
        }
        __syncthreads();
    }
#pragma unroll
    for (int i = 0; i < 4; ++i) {
        int m = m0 + ty * 4 + i;
        if (m >= NNODES) continue;
        int n = n0 + tx * 4;
        float4 o;
        o.x = acc[i][0]; o.y = acc[i][1]; o.z = acc[i][2]; o.w = acc[i][3];
        if (bias) { o.x += bias[n]; o.y += bias[n + 1]; o.z += bias[n + 2]; o.w += bias[n + 3]; }
        *(float4*)&C[(size_t)m * 256 + n] = o;
    }
}

// GEMM3: C[M x 40] = A[M x 256] @ W[256 x 40], one wave per row
__global__ void k_gemm3(const float* __restrict__ A, const float* __restrict__ W,
                        float* __restrict__ C) {
    __shared__ float aS[4][256];
    int m0 = blockIdx.x * 4;
    int t = threadIdx.x;
    for (int j = t; j < 4 * 256; j += 256) {
        int r = j >> 8, k = j & 255;
        aS[r][k] = A[(size_t)(m0 + r) * 256 + k];
    }
    __syncthreads();
    int w = t >> 6, lane = t & 63;
    if (lane >= 40) return;
    float acc0 = 0.f, acc1 = 0.f;
#pragma unroll 8
    for (int k = 0; k < 256; k += 2) {
        acc0 = fmaf(aS[w][k],     W[k * 40 + lane],       acc0);
        acc1 = fmaf(aS[w][k + 1], W[(k + 1) * 40 + lane], acc1);
    }
    C[(size_t)(m0 + w) * 40 + lane] = acc0 + acc1;
}

// ---------------- BatchNorm ----------------

__global__ void k_bnstats(const float* __restrict__ H, float* __restrict__ sums) {
    int c = threadIdx.x;  // 256
    size_t r0 = (size_t)blockIdx.x * 256;
    float s = 0.f, s2 = 0.f;
    for (int i = 0; i < 256; ++i) {
        size_t m = r0 + i;
        if (m >= NNODES) break;
        float v = H[m * 256 + c];
        s += v; s2 += v * v;
    }
    atomicAdd(&sums[c], s);
    atomicAdd(&sums[256 + c], s2);
}

__global__ void k_bnfin(const float* __restrict__ sums, const float* __restrict__ g,
                        const float* __restrict__ be, float* __restrict__ scsh) {
    int c = threadIdx.x;
    float mean = sums[c] * (1.0f / NNODES);
    float var  = sums[256 + c] * (1.0f / NNODES) - mean * mean;
    float sc = g[c] * rsqrtf(var + BN_EPS);
    scsh[c] = sc;
    scsh[256 + c] = be[c] - mean * sc;
}

__global__ void k_bnrelu(float* __restrict__ H, const float* __restrict__ scsh) {
    size_t idx = (size_t)blockIdx.x * 256 + threadIdx.x;  // float4 index; N*64 total
    int c4 = (int)(idx & 63);
    float4 v = ((float4*)H)[idx];
    float4 sc = ((const float4*)scsh)[c4];
    float4 sh = ((const float4*)(scsh + 256))[c4];
    v.x = fmaxf(fmaf(v.x, sc.x, sh.x), 0.f);
    v.y = fmaxf(fmaf(v.y, sc.y, sh.y), 0.f);
    v.z = fmaxf(fmaf(v.z, sc.z, sh.z), 0.f);
    v.w = fmaxf(fmaf(v.w, sc.w, sh.w), 0.f);
    ((float4*)H)[idx] = v;
}

// ---------------- log_softmax over 40 classes: one wave per row ----------------

__global__ void k_lsm(const float* __restrict__ H, float* __restrict__ out) {
    int t = threadIdx.x;
    int w = t >> 6, lane = t & 63;
    int m = blockIdx.x * 4 + w;
    if (m >= NNODES) return;
    float v = (lane < 40) ? H[(size_t)m * 40 + lane] : -INFINITY;
    float mx = v;
    for (int o = 32; o > 0; o >>= 1) mx = fmaxf(mx, __shfl_xor(mx, o));
    float e = (lane < 40) ? expf(v - mx) : 0.f;
    float s = e;
    for (int o = 32; o > 0; o >>= 1) s += __shfl_xor(s, o);
    if (lane < 40) out[(size_t)m * 40 + lane] = v - mx - logf(s);
}

// ---------------- launch ----------------

extern "C" void kernel_launch(void* const* d_in, const int* in_sizes, int n_in,
                              void* d_out, int out_size, void* d_ws, size_t ws_size,
                              hipStream_t stream) {
    const float* x  = (const float*)d_in[0];
    const int*   ei = (const int*)d_in[1];       // int32 on device (harness converts integers)
    const float* W1 = (const float*)d_in[2];
    const float* b1 = (const float*)d_in[3];
    const float* W2 = (const float*)d_in[4];
    const float* b2 = (const float*)d_in[5];
    const float* W3 = (const float*)d_in[6];
    const float* b3 = (const float*)d_in[7];
    const float* g1 = (const float*)d_in[8];
    const float* be1 = (const float*)d_in[9];
    const float* g2 = (const float*)d_in[10];
    const float* be2 = (const float*)d_in[11];
    float* out = (float*)d_out;

    const int* esrc = ei;
    const int* edst = ei + NEDGES;

    char* p = (char*)d_ws;
    auto alloc = [&](size_t bytes) { char* r = p; p += (bytes + 511) & ~(size_t)511; return r; };
    float* dinv     = (float*)alloc((size_t)NNODES * 4);
    int*   cnt      = (int*)  alloc((size_t)NNODES * 4);
    int*   rowstart = (int*)  alloc((size_t)(NNODES + 1) * 4);
    int*   cursor   = (int*)  alloc((size_t)NNODES * 4);
    int*   chunksums= (int*)  alloc((size_t)NCH * 4);
    float* stats    = (float*)alloc((size_t)2048 * 4);   // sums1|scsh1|sums2|scsh2
    int2*  pairs    = (int2*) alloc((size_t)NEDGES * 8);
    float* bufA     = (float*)alloc((size_t)NNODES * 256 * 4);
    float* bufB     = (float*)alloc((size_t)NNODES * 256 * 4);

    float* sums1 = stats;        float* scsh1 = stats + 512;
    float* sums2 = stats + 1024; float* scsh2 = stats + 1536;

    hipMemsetAsync(cnt, 0, (size_t)NNODES * 4, stream);
    hipMemsetAsync(stats, 0, (size_t)2048 * 4, stream);

    const int EB = NEDGES / 256;      // 12500
    const int NB = NCH;               // 391

    // CSR build
    k_hist<<<EB, 256, 0, stream>>>(edst, cnt);
    k_dinv<<<NB, 256, 0, stream>>>(cnt, dinv);
    k_chunksum<<<NB, 256, 0, stream>>>(cnt, chunksums);
    k_scan1<<<1, 1, 0, stream>>>(chunksums, rowstart);
    k_scan2<<<NB, 256, 0, stream>>>(cnt, chunksums, rowstart, cursor);
    k_scatter<<<EB, 256, 0, stream>>>(esrc, edst, dinv, cursor, pairs);

    dim3 ggrid((NNODES + 63) / 64, 4);

    // Layer 1: P = Agg(x) [128-wide]; h1 = P@W1 + b1; BN+ReLU
    k_agg<128><<<NNODES, 128, 0, stream>>>(x, bufA, pairs, rowstart, dinv, nullptr);
    k_gemm64<128><<<ggrid, 256, 0, stream>>>(bufA, W1, b1, bufB);
    k_bnstats<<<NB, 256, 0, stream>>>(bufB, sums1);
    k_bnfin<<<1, 256, 0, stream>>>(sums1, g1, be1, scsh1);
    k_bnrelu<<<NNODES / 4, 256, 0, stream>>>(bufB, scsh1);  // N*64/256 = 25000 blocks

    // Layer 2: t = a1@W2; h2 = Agg(t) + b2; BN+ReLU
    k_gemm64<256><<<ggrid, 256, 0, stream>>>(bufB, W2, nullptr, bufA);
    k_agg<256><<<NNODES, 256, 0, stream>>>(bufA, bufB, pairs, rowstart, dinv, b2);
    k_bnstats<<<NB, 256, 0, stream>>>(bufB, sums2);
    k_bnfin<<<1, 256, 0, stream>>>(sums2, g2, be2, scsh2);
    k_bnrelu<<<NNODES / 4, 256, 0, stream>>>(bufB, scsh2);

    // Layer 3: t3 = a2@W3 [N x 40]; h3 = Agg(t3) + b3; log_softmax
    k_gemm3<<<NNODES / 4, 256, 0, stream>>>(bufB, W3, bufA);
    k_agg40<<<NNODES / 4, 256, 0, stream>>>(bufA, bufB, pairs, rowstart, dinv, b3);
    k_lsm<<<NNODES / 4, 256, 0, stream>>>(bufB, out);
}

// Round 3
// 1490.797 us; speedup vs baseline: 1.5100x; 1.5100x over previous
//
#include <hip/hip_runtime.h>
#include <hip/hip_bf16.h>
#include <math.h>

#define NNODES 100000
#define NEDGES 3200000
#define BN_EPS 1e-5f
#define NCH 391   // ceil(NNODES/256)

typedef unsigned int uint;
typedef unsigned short ushort;

__device__ inline float bflo(uint u) { return __uint_as_float(u << 16); }
__device__ inline float bfhi(uint u) { return __uint_as_float(u & 0xffff0000u); }
__device__ inline ushort f2bf(float f) {
    __hip_bfloat16 h = __float2bfloat16(f);   // RTN
    union { __hip_bfloat16 b; ushort u; } c; c.b = h; return c.u;
}

// ---------------- CSR build (edge_index arrives as int32) ----------------

__global__ void k_hist(const int* __restrict__ dst, int* __restrict__ cnt) {
    int e = blockIdx.x * 256 + threadIdx.x;
    if (e < NEDGES) atomicAdd(&cnt[dst[e]], 1);
}

__global__ void k_dinv(const int* __restrict__ cnt, float* __restrict__ dinv) {
    int i = blockIdx.x * 256 + threadIdx.x;
    if (i < NNODES) dinv[i] = rsqrtf((float)cnt[i] + 1.0f);  // deg includes self-loop
}

__global__ void k_chunksum(const int* __restrict__ cnt, int* __restrict__ chunksums) {
    __shared__ int s[256];
    int i = blockIdx.x * 256 + threadIdx.x;
    s[threadIdx.x] = (i < NNODES) ? cnt[i] : 0;
    __syncthreads();
    for (int o = 128; o > 0; o >>= 1) {
        if (threadIdx.x < o) s[threadIdx.x] += s[threadIdx.x + o];
        __syncthreads();
    }
    if (threadIdx.x == 0) chunksums[blockIdx.x] = s[0];
}

__global__ void k_scan1(int* __restrict__ chunksums, int* __restrict__ rowstart) {
    if (threadIdx.x == 0 && blockIdx.x == 0) {
        int run = 0;
        for (int i = 0; i < NCH; ++i) { int v = chunksums[i]; chunksums[i] = run; run += v; }
        rowstart[NNODES] = run;   // == NEDGES
    }
}

__global__ void k_scan2(const int* __restrict__ cnt, const int* __restrict__ chunkbase,
                        int* __restrict__ rowstart, int* __restrict__ cursor) {
    __shared__ int s[256];
    int t = threadIdx.x;
    int i = blockIdx.x * 256 + t;
    int v = (i < NNODES) ? cnt[i] : 0;
    s[t] = v;
    __syncthreads();
    for (int o = 1; o < 256; o <<= 1) {
        int add = (t >= o) ? s[t - o] : 0;
        __syncthreads();
        s[t] += add;
        __syncthreads();
    }
    if (i < NNODES) {
        int excl = s[t] - v + chunkbase[blockIdx.x];
        rowstart[i] = excl;
        cursor[i]   = excl;
    }
}

__global__ void k_scatter(const int* __restrict__ src, const int* __restrict__ dst,
                          const float* __restrict__ dinv, int* __restrict__ cursor,
                          int2* __restrict__ pairs) {
    int e = blockIdx.x * 256 + threadIdx.x;
    if (e >= NEDGES) return;
    int s = src[e], d = dst[e];
    int p = atomicAdd(&cursor[d], 1);
    float w = dinv[s] * dinv[d];
    pairs[p] = make_int2(s, __float_as_int(w));
}

// ---------------- bf16 aggregation: Y[d] = sum_e w_e*X[col] + dinv[d]^2*X[d] (+bias) ----
// X is bf16 [N x F]; each thread owns a feature PAIR (4-byte loads), fp32 accum.
// NPB nodes/block, F/2 threads per node; waves never span nodes (F>=128).

template <int F, int NPB>
__global__ __launch_bounds__(256) void k_aggb(
    const ushort* __restrict__ X, float* __restrict__ Y,
    const int2* __restrict__ pairs, const int* __restrict__ rowstart,
    const float* __restrict__ dinv, const float* __restrict__ bias) {
    constexpr int TPN = F / 2;
    const int sub = threadIdx.x / TPN;
    const int t   = threadIdx.x % TPN;
    const int d   = blockIdx.x * NPB + sub;
    if (d >= NNODES) return;
    const int r0 = rowstart[d], r1 = rowstart[d + 1];
    float a0 = 0.f, a1 = 0.f;
    int p = r0;
    for (; p + 4 <= r1; p += 4) {   // 4 independent gathers in flight
        int2 e0 = pairs[p], e1 = pairs[p + 1], e2 = pairs[p + 2], e3 = pairs[p + 3];
        uint u0 = *(const uint*)(X + (size_t)e0.x * F + 2 * t);
        uint u1 = *(const uint*)(X + (size_t)e1.x * F + 2 * t);
        uint u2 = *(const uint*)(X + (size_t)e2.x * F + 2 * t);
        uint u3 = *(const uint*)(X + (size_t)e3.x * F + 2 * t);
        float w0 = __int_as_float(e0.y), w1 = __int_as_float(e1.y);
        float w2 = __int_as_float(e2.y), w3 = __int_as_float(e3.y);
        a0 = fmaf(w0, bflo(u0), a0); a1 = fmaf(w0, bfhi(u0), a1);
        a0 = fmaf(w1, bflo(u1), a0); a1 = fmaf(w1, bfhi(u1), a1);
        a0 = fmaf(w2, bflo(u2), a0); a1 = fmaf(w2, bfhi(u2), a1);
        a0 = fmaf(w3, bflo(u3), a0); a1 = fmaf(w3, bfhi(u3), a1);
    }
    for (; p < r1; ++p) {
        int2 e = pairs[p];
        uint u = *(const uint*)(X + (size_t)e.x * F + 2 * t);
        float w = __int_as_float(e.y);
        a0 = fmaf(w, bflo(u), a0); a1 = fmaf(w, bfhi(u), a1);
    }
    float di = dinv[d], ws = di * di;
    uint us = *(const uint*)(X + (size_t)d * F + 2 * t);
    a0 = fmaf(ws, bflo(us), a0); a1 = fmaf(ws, bfhi(us), a1);
    if (bias) { a0 += bias[2 * t]; a1 += bias[2 * t + 1]; }
    *(float2*)(Y + (size_t)d * F + 2 * t) = make_float2(a0, a1);
}

// 40-wide bf16 aggregation: one wave per node, lanes 0..19 own feature pairs
__global__ void k_agg40b(const ushort* __restrict__ X, float* __restrict__ Y,
                         const int2* __restrict__ pairs, const int* __restrict__ rowstart,
                         const float* __restrict__ dinv, const float* __restrict__ bias) {
    int w = threadIdx.x >> 6, lane = threadIdx.x & 63;
    int d = blockIdx.x * 4 + w;
    if (d >= NNODES || lane >= 20) return;
    const int r0 = rowstart[d], r1 = rowstart[d + 1];
    float a0 = 0.f, a1 = 0.f;
    int p = r0;
    for (; p + 4 <= r1; p += 4) {
        int2 e0 = pairs[p], e1 = pairs[p + 1], e2 = pairs[p + 2], e3 = pairs[p + 3];
        uint u0 = *(const uint*)(X + (size_t)e0.x * 40 + 2 * lane);
        uint u1 = *(const uint*)(X + (size_t)e1.x * 40 + 2 * lane);
        uint u2 = *(const uint*)(X + (size_t)e2.x * 40 + 2 * lane);
        uint u3 = *(const uint*)(X + (size_t)e3.x * 40 + 2 * lane);
        float w0 = __int_as_float(e0.y), w1 = __int_as_float(e1.y);
        float w2 = __int_as_float(e2.y), w3 = __int_as_float(e3.y);
        a0 = fmaf(w0, bflo(u0), a0); a1 = fmaf(w0, bfhi(u0), a1);
        a0 = fmaf(w1, bflo(u1), a0); a1 = fmaf(w1, bfhi(u1), a1);
        a0 = fmaf(w2, bflo(u2), a0); a1 = fmaf(w2, bfhi(u2), a1);
        a0 = fmaf(w3, bflo(u3), a0); a1 = fmaf(w3, bfhi(u3), a1);
    }
    for (; p < r1; ++p) {
        int2 e = pairs[p];
        uint u = *(const uint*)(X + (size_t)e.x * 40 + 2 * lane);
        float w = __int_as_float(e.y);
        a0 = fmaf(w, bflo(u), a0); a1 = fmaf(w, bfhi(u), a1);
    }
    float di = dinv[d], ws = di * di;
    uint us = *(const uint*)(X + (size_t)d * 40 + 2 * lane);
    a0 = fmaf(ws, bflo(us), a0); a1 = fmaf(ws, bfhi(us), a1);
    a0 += bias[2 * lane]; a1 += bias[2 * lane + 1];
    *(float2*)(Y + (size_t)d * 40 + 2 * lane) = make_float2(a0, a1);
}

// ---------------- fp32 -> bf16 bulk convert (x) ----------------

__global__ void k_xtobf16(const float* __restrict__ X, ushort* __restrict__ O) {
    int i = blockIdx.x * 256 + threadIdx.x;   // one float4 each; N*128/4 total
    float4 v = ((const float4*)X)[i];
    ushort4 o; o.x = f2bf(v.x); o.y = f2bf(v.y); o.z = f2bf(v.z); o.w = f2bf(v.w);
    ((ushort4*)O)[i] = o;
}

// ---------------- GEMM: C[M x 256] = A[M x K] @ W[K x 256] (+bias) ----------------

template <int K, bool BF16OUT>
__global__ __launch_bounds__(256) void k_gemm64(
    const float* __restrict__ A, const float* __restrict__ W,
    const float* __restrict__ bias, void* __restrict__ C) {
    __shared__ __align__(16) float As[32][68];
    __shared__ __align__(16) float Ws[32][68];
    const int m0 = blockIdx.x * 64;
    const int n0 = blockIdx.y * 64;
    const int tid = threadIdx.x;
    const int tx = tid & 15, ty = tid >> 4;
    const int kk_a = tid & 31, rg = tid >> 5;
    const int kk_w = tid >> 3, cq = tid & 7;
    float acc[4][4] = {};
    for (int k0 = 0; k0 < K; k0 += 32) {
#pragma unroll
        for (int j = 0; j < 8; ++j) {
            int m = m0 + rg * 8 + j;
            As[kk_a][rg * 8 + j] = (m < NNODES) ? A[(size_t)m * K + k0 + kk_a] : 0.f;
        }
        {
            const float* srcp = &W[(size_t)(k0 + kk_w) * 256 + n0 + cq * 8];
            *(float4*)&Ws[kk_w][cq * 8]     = *(const float4*)srcp;
            *(float4*)&Ws[kk_w][cq * 8 + 4] = *(const float4*)(srcp + 4);
        }
        __syncthreads();
#pragma unroll
        for (int kk = 0; kk < 32; ++kk) {
            float ar[4], br[4];
            *(float4*)ar = *(const float4*)&As[kk][ty * 4];
            *(float4*)br = *(const float4*)&Ws[kk][tx * 4];
#pragma unroll
            for (int i = 0; i < 4; ++i)
#pragma unroll
                for (int j = 0; j < 4; ++j)
                    acc[i][j] = fmaf(ar[i], br[j], acc[i][j]);
        }
        __syncthreads();
    }
#pragma unroll
    for (int i = 0; i < 4; ++i) {
        int m = m0 + ty * 4 + i;
        if (m >= NNODES) continue;
        int n = n0 + tx * 4;
        float4 o;
        o.x = acc[i][0]; o.y = acc[i][1]; o.z = acc[i][2]; o.w = acc[i][3];
        if (bias) { o.x += bias[n]; o.y += bias[n + 1]; o.z += bias[n + 2]; o.w += bias[n + 3]; }
        if (BF16OUT) {
            ushort4 q; q.x = f2bf(o.x); q.y = f2bf(o.y); q.z = f2bf(o.z); q.w = f2bf(o.w);
            *(ushort4*)&((ushort*)C)[(size_t)m * 256 + n] = q;
        } else {
            *(float4*)&((float*)C)[(size_t)m * 256 + n] = o;
        }
    }
}

// GEMM3: C[M x 40](bf16) = A[M x 256] @ W[256 x 40], one wave per row
__global__ void k_gemm3(const float* __restrict__ A, const float* __restrict__ W,
                        ushort* __restrict__ C) {
    __shared__ float aS[4][256];
    int m0 = blockIdx.x * 4;
    int t = threadIdx.x;
    for (int j = t; j < 4 * 256; j += 256) {
        int r = j >> 8, k = j & 255;
        aS[r][k] = A[(size_t)(m0 + r) * 256 + k];
    }
    __syncthreads();
    int w = t >> 6, lane = t & 63;
    if (lane >= 40) return;
    float acc0 = 0.f, acc1 = 0.f;
#pragma unroll 8
    for (int k = 0; k < 256; k += 2) {
        acc0 = fmaf(aS[w][k],     W[k * 40 + lane],       acc0);
        acc1 = fmaf(aS[w][k + 1], W[(k + 1) * 40 + lane], acc1);
    }
    C[(size_t)(m0 + w) * 40 + lane] = f2bf(acc0 + acc1);
}

// ---------------- BatchNorm ----------------

__global__ void k_bnstats(const float* __restrict__ H, float* __restrict__ sums) {
    int c = threadIdx.x;
    size_t r0 = (size_t)blockIdx.x * 256;
    float s = 0.f, s2 = 0.f;
    for (int i = 0; i < 256; ++i) {
        size_t m = r0 + i;
        if (m >= NNODES) break;
        float v = H[m * 256 + c];
        s += v; s2 += v * v;
    }
    atomicAdd(&sums[c], s);
    atomicAdd(&sums[256 + c], s2);
}

__global__ void k_bnfin(const float* __restrict__ sums, const float* __restrict__ g,
                        const float* __restrict__ be, float* __restrict__ scsh) {
    int c = threadIdx.x;
    float mean = sums[c] * (1.0f / NNODES);
    float var  = sums[256 + c] * (1.0f / NNODES) - mean * mean;
    float sc = g[c] * rsqrtf(var + BN_EPS);
    scsh[c] = sc;
    scsh[256 + c] = be[c] - mean * sc;
}

__global__ void k_bnrelu(float* __restrict__ H, const float* __restrict__ scsh) {
    size_t idx = (size_t)blockIdx.x * 256 + threadIdx.x;
    int c4 = (int)(idx & 63);
    float4 v = ((float4*)H)[idx];
    float4 sc = ((const float4*)scsh)[c4];
    float4 sh = ((const float4*)(scsh + 256))[c4];
    v.x = fmaxf(fmaf(v.x, sc.x, sh.x), 0.f);
    v.y = fmaxf(fmaf(v.y, sc.y, sh.y), 0.f);
    v.z = fmaxf(fmaf(v.z, sc.z, sh.z), 0.f);
    v.w = fmaxf(fmaf(v.w, sc.w, sh.w), 0.f);
    ((float4*)H)[idx] = v;
}

// ---------------- log_softmax over 40 classes ----------------

__global__ void k_lsm(const float* __restrict__ H, float* __restrict__ out) {
    int t = threadIdx.x;
    int w = t >> 6, lane = t & 63;
    int m = blockIdx.x * 4 + w;
    if (m >= NNODES) return;
    float v = (lane < 40) ? H[(size_t)m * 40 + lane] : -INFINITY;
    float mx = v;
    for (int o = 32; o > 0; o >>= 1) mx = fmaxf(mx, __shfl_xor(mx, o));
    float e = (lane < 40) ? expf(v - mx) : 0.f;
    float s = e;
    for (int o = 32; o > 0; o >>= 1) s += __shfl_xor(s, o);
    if (lane < 40) out[(size_t)m * 40 + lane] = v - mx - logf(s);
}

// ---------------- launch ----------------

extern "C" void kernel_launch(void* const* d_in, const int* in_sizes, int n_in,
                              void* d_out, int out_size, void* d_ws, size_t ws_size,
                              hipStream_t stream) {
    const float* x  = (const float*)d_in[0];
    const int*   ei = (const int*)d_in[1];
    const float* W1 = (const float*)d_in[2];
    const float* b1 = (const float*)d_in[3];
    const float* W2 = (const float*)d_in[4];
    const float* b2 = (const float*)d_in[5];
    const float* W3 = (const float*)d_in[6];
    const float* b3 = (const float*)d_in[7];
    const float* g1 = (const float*)d_in[8];
    const float* be1 = (const float*)d_in[9];
    const float* g2 = (const float*)d_in[10];
    const float* be2 = (const float*)d_in[11];
    float* out = (float*)d_out;

    const int* esrc = ei;
    const int* edst = ei + NEDGES;

    char* p = (char*)d_ws;
    auto alloc = [&](size_t bytes) { char* r = p; p += (bytes + 511) & ~(size_t)511; return r; };
    float* dinv     = (float*)alloc((size_t)NNODES * 4);
    int*   cnt      = (int*)  alloc((size_t)NNODES * 4);
    int*   rowstart = (int*)  alloc((size_t)(NNODES + 1) * 4);
    int*   cursor   = (int*)  alloc((size_t)NNODES * 4);
    int*   chunksums= (int*)  alloc((size_t)NCH * 4);
    float* stats    = (float*)alloc((size_t)2048 * 4);
    int2*  pairs    = (int2*) alloc((size_t)NEDGES * 8);
    float* bufA     = (float*)alloc((size_t)NNODES * 256 * 4);
    float* bufB     = (float*)alloc((size_t)NNODES * 256 * 4);

    // Aliased views (stream-ordered lifetimes, see timeline below):
    ushort* xbf16  = (ushort*)bufB;                        // dead before GEMM1 writes bufB
    float*  P      = bufA;                                 // Agg(x), N x 128 f32 (first half)
    ushort* tbf16  = (ushort*)(bufA + (size_t)NNODES*128); // GEMM2 out, N x 256 bf16 (2nd half)
    ushort* t3bf16 = (ushort*)bufA;                        // GEMM3 out, N x 40 bf16 (8 MB)
    float*  h3     = bufA + (size_t)NNODES * 64;           // agg40 out, N x 40 f32 (at 25.6 MB)

    float* sums1 = stats;        float* scsh1 = stats + 512;
    float* sums2 = stats + 1024; float* scsh2 = stats + 1536;

    hipMemsetAsync(cnt, 0, (size_t)NNODES * 4, stream);
    hipMemsetAsync(stats, 0, (size_t)2048 * 4, stream);

    const int EB = NEDGES / 256;   // 12500
    const int NB = NCH;            // 391

    // CSR build
    k_hist<<<EB, 256, 0, stream>>>(edst, cnt);
    k_dinv<<<NB, 256, 0, stream>>>(cnt, dinv);
    k_chunksum<<<NB, 256, 0, stream>>>(cnt, chunksums);
    k_scan1<<<1, 1, 0, stream>>>(chunksums, rowstart);
    k_scan2<<<NB, 256, 0, stream>>>(cnt, chunksums, rowstart, cursor);
    k_scatter<<<EB, 256, 0, stream>>>(esrc, edst, dinv, cursor, pairs);

    dim3 ggrid((NNODES + 63) / 64, 4);

    // Layer 1: xb = bf16(x); P = Agg(xb); h1 = P@W1 + b1 -> bufB; BN+ReLU
    k_xtobf16<<<NNODES * 128 / 4 / 256, 256, 0, stream>>>(x, xbf16);
    k_aggb<128, 4><<<NNODES / 4, 256, 0, stream>>>(xbf16, P, pairs, rowstart, dinv, nullptr);
    k_gemm64<128, false><<<ggrid, 256, 0, stream>>>(P, W1, b1, bufB);
    k_bnstats<<<NB, 256, 0, stream>>>(bufB, sums1);
    k_bnfin<<<1, 256, 0, stream>>>(sums1, g1, be1, scsh1);
    k_bnrelu<<<NNODES / 4, 256, 0, stream>>>(bufB, scsh1);

    // Layer 2: t = a1@W2 (bf16) -> tbf16; h2 = Agg(t) + b2 -> bufB; BN+ReLU
    k_gemm64<256, true><<<ggrid, 256, 0, stream>>>(bufB, W2, nullptr, tbf16);
    k_aggb<256, 2><<<NNODES / 2, 256, 0, stream>>>(tbf16, bufB, pairs, rowstart, dinv, b2);
    k_bnstats<<<NB, 256, 0, stream>>>(bufB, sums2);
    k_bnfin<<<1, 256, 0, stream>>>(sums2, g2, be2, scsh2);
    k_bnrelu<<<NNODES / 4, 256, 0, stream>>>(bufB, scsh2);

    // Layer 3: t3 = a2@W3 (bf16); h3 = Agg(t3) + b3; log_softmax
    k_gemm3<<<NNODES / 4, 256, 0, stream>>>(bufB, W3, t3bf16);
    k_agg40b<<<NNODES / 4, 256, 0, stream>>>(t3bf16, h3, pairs, rowstart, dinv, b3);
    k_lsm<<<NNODES / 4, 256, 0, stream>>>(h3, out);
}

// Round 4
// 1252.730 us; speedup vs baseline: 1.7970x; 1.1900x over previous
//
#include <hip/hip_runtime.h>
#include <hip/hip_bf16.h>
#include <math.h>

#define NNODES 100000
#define NEDGES 3200000
#define BN_EPS 1e-5f
#define NCH 391   // ceil(NNODES/256)

typedef unsigned int uint;
typedef unsigned short ushort;
typedef __attribute__((ext_vector_type(8))) short bf16x8;
typedef __attribute__((ext_vector_type(4))) float f32x4;

__device__ inline float bflo(uint u) { return __uint_as_float(u << 16); }
__device__ inline float bfhi(uint u) { return __uint_as_float(u & 0xffff0000u); }
__device__ inline ushort f2bf(float f) {
    __hip_bfloat16 h = __float2bfloat16(f);
    union { __hip_bfloat16 b; ushort u; } c; c.b = h; return c.u;
}

// ---------------- CSR build (edge_index arrives as int32) ----------------

__global__ void k_hist(const int* __restrict__ dst, int* __restrict__ cnt) {
    int e = blockIdx.x * 256 + threadIdx.x;
    if (e < NEDGES) atomicAdd(&cnt[dst[e]], 1);
}

__global__ void k_dinv(const int* __restrict__ cnt, float* __restrict__ dinv) {
    int i = blockIdx.x * 256 + threadIdx.x;
    if (i < NNODES) dinv[i] = rsqrtf((float)cnt[i] + 1.0f);
}

__global__ void k_chunksum(const int* __restrict__ cnt, int* __restrict__ chunksums) {
    __shared__ int s[256];
    int i = blockIdx.x * 256 + threadIdx.x;
    s[threadIdx.x] = (i < NNODES) ? cnt[i] : 0;
    __syncthreads();
    for (int o = 128; o > 0; o >>= 1) {
        if (threadIdx.x < o) s[threadIdx.x] += s[threadIdx.x + o];
        __syncthreads();
    }
    if (threadIdx.x == 0) chunksums[blockIdx.x] = s[0];
}

__global__ void k_scan1(int* __restrict__ chunksums, int* __restrict__ rowstart) {
    if (threadIdx.x == 0 && blockIdx.x == 0) {
        int run = 0;
        for (int i = 0; i < NCH; ++i) { int v = chunksums[i]; chunksums[i] = run; run += v; }
        rowstart[NNODES] = run;
    }
}

__global__ void k_scan2(const int* __restrict__ cnt, const int* __restrict__ chunkbase,
                        int* __restrict__ rowstart, int* __restrict__ cursor) {
    __shared__ int s[256];
    int t = threadIdx.x;
    int i = blockIdx.x * 256 + t;
    int v = (i < NNODES) ? cnt[i] : 0;
    s[t] = v;
    __syncthreads();
    for (int o = 1; o < 256; o <<= 1) {
        int add = (t >= o) ? s[t - o] : 0;
        __syncthreads();
        s[t] += add;
        __syncthreads();
    }
    if (i < NNODES) {
        int excl = s[t] - v + chunkbase[blockIdx.x];
        rowstart[i] = excl;
        cursor[i]   = excl;
    }
}

__global__ void k_scatter(const int* __restrict__ src, const int* __restrict__ dst,
                          const float* __restrict__ dinv, int* __restrict__ cursor,
                          int2* __restrict__ pairs) {
    int e = blockIdx.x * 256 + threadIdx.x;
    if (e >= NEDGES) return;
    int s = src[e], d = dst[e];
    int p = atomicAdd(&cursor[d], 1);
    float w = dinv[s] * dinv[d];
    pairs[p] = make_int2(s, __float_as_int(w));
}

// ---------------- bf16 aggregation, one wave per node ----------------
// X bf16 [N x F]; lane owns VEC=F/64 channels; fp32 accum; 4 gathers in flight.

template <int F, bool BF16OUT>
__global__ __launch_bounds__(256) void k_aggb(
    const ushort* __restrict__ X, void* __restrict__ Yv,
    const int2* __restrict__ pairs, const int* __restrict__ rowstart,
    const float* __restrict__ dinv, const float* __restrict__ bias) {
    constexpr int VEC = F / 64;   // 2 or 4
    constexpr int NU  = VEC / 2;  // uints per lane (1 or 2)
    const int sub = threadIdx.x >> 6;
    const int t   = threadIdx.x & 63;
    const int d   = blockIdx.x * 4 + sub;
    if (d >= NNODES) return;
    const int r0 = rowstart[d], r1 = rowstart[d + 1];
    const size_t cb = (size_t)VEC * t;
    float acc[VEC] = {};
    int p = r0;
    for (; p + 4 <= r1; p += 4) {
        int2 e0 = pairs[p], e1 = pairs[p+1], e2 = pairs[p+2], e3 = pairs[p+3];
        if constexpr (NU == 2) {
            uint2 u0 = *(const uint2*)(X + (size_t)e0.x * F + cb);
            uint2 u1 = *(const uint2*)(X + (size_t)e1.x * F + cb);
            uint2 u2 = *(const uint2*)(X + (size_t)e2.x * F + cb);
            uint2 u3 = *(const uint2*)(X + (size_t)e3.x * F + cb);
            float w0 = __int_as_float(e0.y), w1 = __int_as_float(e1.y);
            float w2 = __int_as_float(e2.y), w3 = __int_as_float(e3.y);
            acc[0]=fmaf(w0,bflo(u0.x),acc[0]); acc[1]=fmaf(w0,bfhi(u0.x),acc[1]);
            acc[2]=fmaf(w0,bflo(u0.y),acc[2]); acc[3]=fmaf(w0,bfhi(u0.y),acc[3]);
            acc[0]=fmaf(w1,bflo(u1.x),acc[0]); acc[1]=fmaf(w1,bfhi(u1.x),acc[1]);
            acc[2]=fmaf(w1,bflo(u1.y),acc[2]); acc[3]=fmaf(w1,bfhi(u1.y),acc[3]);
            acc[0]=fmaf(w2,bflo(u2.x),acc[0]); acc[1]=fmaf(w2,bfhi(u2.x),acc[1]);
            acc[2]=fmaf(w2,bflo(u2.y),acc[2]); acc[3]=fmaf(w2,bfhi(u2.y),acc[3]);
            acc[0]=fmaf(w3,bflo(u3.x),acc[0]); acc[1]=fmaf(w3,bfhi(u3.x),acc[1]);
            acc[2]=fmaf(w3,bflo(u3.y),acc[2]); acc[3]=fmaf(w3,bfhi(u3.y),acc[3]);
        } else {
            uint u0 = *(const uint*)(X + (size_t)e0.x * F + cb);
            uint u1 = *(const uint*)(X + (size_t)e1.x * F + cb);
            uint u2 = *(const uint*)(X + (size_t)e2.x * F + cb);
            uint u3 = *(const uint*)(X + (size_t)e3.x * F + cb);
            float w0 = __int_as_float(e0.y), w1 = __int_as_float(e1.y);
            float w2 = __int_as_float(e2.y), w3 = __int_as_float(e3.y);
            acc[0]=fmaf(w0,bflo(u0),acc[0]); acc[1]=fmaf(w0,bfhi(u0),acc[1]);
            acc[0]=fmaf(w1,bflo(u1),acc[0]); acc[1]=fmaf(w1,bfhi(u1),acc[1]);
            acc[0]=fmaf(w2,bflo(u2),acc[0]); acc[1]=fmaf(w2,bfhi(u2),acc[1]);
            acc[0]=fmaf(w3,bflo(u3),acc[0]); acc[1]=fmaf(w3,bfhi(u3),acc[1]);
        }
    }
    for (; p < r1; ++p) {
        int2 e = pairs[p];
        float w = __int_as_float(e.y);
        if constexpr (NU == 2) {
            uint2 u = *(const uint2*)(X + (size_t)e.x * F + cb);
            acc[0]=fmaf(w,bflo(u.x),acc[0]); acc[1]=fmaf(w,bfhi(u.x),acc[1]);
            acc[2]=fmaf(w,bflo(u.y),acc[2]); acc[3]=fmaf(w,bfhi(u.y),acc[3]);
        } else {
            uint u = *(const uint*)(X + (size_t)e.x * F + cb);
            acc[0]=fmaf(w,bflo(u),acc[0]); acc[1]=fmaf(w,bfhi(u),acc[1]);
        }
    }
    float di = dinv[d], ws = di * di;
    if constexpr (NU == 2) {
        uint2 u = *(const uint2*)(X + (size_t)d * F + cb);
        acc[0]=fmaf(ws,bflo(u.x),acc[0]); acc[1]=fmaf(ws,bfhi(u.x),acc[1]);
        acc[2]=fmaf(ws,bflo(u.y),acc[2]); acc[3]=fmaf(ws,bfhi(u.y),acc[3]);
    } else {
        uint u = *(const uint*)(X + (size_t)d * F + cb);
        acc[0]=fmaf(ws,bflo(u),acc[0]); acc[1]=fmaf(ws,bfhi(u),acc[1]);
    }
    if (bias) {
#pragma unroll
        for (int j = 0; j < VEC; ++j) acc[j] += bias[cb + j];
    }
    if constexpr (BF16OUT) {
        uint* Y = (uint*)Yv;
        uint o0 = (uint)f2bf(acc[0]) | ((uint)f2bf(acc[1]) << 16);
        if constexpr (NU == 2) {
            uint o1 = (uint)f2bf(acc[2]) | ((uint)f2bf(acc[3]) << 16);
            *(uint2*)(Y + (size_t)d * (F/2) + cb/2) = make_uint2(o0, o1);
        } else {
            Y[(size_t)d * (F/2) + cb/2] = o0;
        }
    } else {
        float* Y = (float*)Yv;
        if constexpr (NU == 2) {
            float4 o; o.x=acc[0]; o.y=acc[1]; o.z=acc[2]; o.w=acc[3];
            *(float4*)(Y + (size_t)d * F + cb) = o;
        } else {
            *(float2*)(Y + (size_t)d * F + cb) = make_float2(acc[0], acc[1]);
        }
    }
}

// 40-wide bf16 aggregation: one wave per node, lanes 0..19 own feature pairs
__global__ void k_agg40b(const ushort* __restrict__ X, float* __restrict__ Y,
                         const int2* __restrict__ pairs, const int* __restrict__ rowstart,
                         const float* __restrict__ dinv, const float* __restrict__ bias) {
    int w = threadIdx.x >> 6, lane = threadIdx.x & 63;
    int d = blockIdx.x * 4 + w;
    if (d >= NNODES || lane >= 20) return;
    const int r0 = rowstart[d], r1 = rowstart[d + 1];
    float a0 = 0.f, a1 = 0.f;
    int p = r0;
    for (; p + 4 <= r1; p += 4) {
        int2 e0 = pairs[p], e1 = pairs[p+1], e2 = pairs[p+2], e3 = pairs[p+3];
        uint u0 = *(const uint*)(X + (size_t)e0.x * 40 + 2*lane);
        uint u1 = *(const uint*)(X + (size_t)e1.x * 40 + 2*lane);
        uint u2 = *(const uint*)(X + (size_t)e2.x * 40 + 2*lane);
        uint u3 = *(const uint*)(X + (size_t)e3.x * 40 + 2*lane);
        float w0 = __int_as_float(e0.y), w1 = __int_as_float(e1.y);
        float w2 = __int_as_float(e2.y), w3 = __int_as_float(e3.y);
        a0=fmaf(w0,bflo(u0),a0); a1=fmaf(w0,bfhi(u0),a1);
        a0=fmaf(w1,bflo(u1),a0); a1=fmaf(w1,bfhi(u1),a1);
        a0=fmaf(w2,bflo(u2),a0); a1=fmaf(w2,bfhi(u2),a1);
        a0=fmaf(w3,bflo(u3),a0); a1=fmaf(w3,bfhi(u3),a1);
    }
    for (; p < r1; ++p) {
        int2 e = pairs[p];
        uint u = *(const uint*)(X + (size_t)e.x * 40 + 2*lane);
        float w_ = __int_as_float(e.y);
        a0=fmaf(w_,bflo(u),a0); a1=fmaf(w_,bfhi(u),a1);
    }
    float di = dinv[d], ws = di * di;
    uint us = *(const uint*)(X + (size_t)d * 40 + 2*lane);
    a0=fmaf(ws,bflo(us),a0); a1=fmaf(ws,bfhi(us),a1);
    a0 += bias[2*lane]; a1 += bias[2*lane+1];
    *(float2*)(Y + (size_t)d * 40 + 2*lane) = make_float2(a0, a1);
}

// ---------------- converts ----------------

__global__ void k_xtobf16(const float* __restrict__ X, ushort* __restrict__ O) {
    int i = blockIdx.x * 256 + threadIdx.x;
    float4 v = ((const float4*)X)[i];
    ushort4 o; o.x=f2bf(v.x); o.y=f2bf(v.y); o.z=f2bf(v.z); o.w=f2bf(v.w);
    ((ushort4*)O)[i] = o;
}

// W [K][256] f32 -> Wt [256][K] bf16
__global__ void k_wconv(const float* __restrict__ W, ushort* __restrict__ Wt, int K) {
    int n = blockIdx.x;
    for (int k = threadIdx.x; k < K; k += 256)
        Wt[n * K + k] = f2bf(W[(size_t)k * 256 + n]);
}

// ---------------- MFMA GEMM: C[M x 256](bf16) = A[M x K](bf16) @ Bt[256 x K]^T ----------------
// 128x128 tile, 4 waves (2x2), 16x16x32 bf16 MFMA, XOR-swizzled LDS.

template <int K>
__global__ __launch_bounds__(256) void k_gmm(
    const ushort* __restrict__ A, const ushort* __restrict__ Bt,
    ushort* __restrict__ C) {
    __shared__ ushort As[128 * 32];
    __shared__ ushort Bs[128 * 32];
    const int m0 = blockIdx.x * 128;
    const int n0 = blockIdx.y * 128;
    const int tid = threadIdx.x;
    const int lane = tid & 63;
    const int wid = tid >> 6;
    const int wr = wid >> 1, wc = wid & 1;
    const int sr1 = tid >> 2, sc = tid & 3;   // staging: row, 16B-chunk
    const int sr2 = sr1 + 64;
    const int ssl1 = sr1 * 32 + ((sc ^ ((sr1 >> 1) & 3)) * 8);
    const int ssl2 = sr2 * 32 + ((sc ^ ((sr2 >> 1) & 3)) * 8);
    const size_t ga1 = (size_t)min(m0 + sr1, NNODES - 1) * K + sc * 8;
    const size_t ga2 = (size_t)min(m0 + sr2, NNODES - 1) * K + sc * 8;
    const size_t gb1 = (size_t)(n0 + sr1) * K + sc * 8;
    const size_t gb2 = (size_t)(n0 + sr2) * K + sc * 8;
    const int kc = lane >> 4, rr = lane & 15;
    f32x4 acc[4][4] = {};
    for (int k0 = 0; k0 < K; k0 += 32) {
        bf16x8 av1 = *(const bf16x8*)(A + ga1 + k0);
        bf16x8 av2 = *(const bf16x8*)(A + ga2 + k0);
        bf16x8 bv1 = *(const bf16x8*)(Bt + gb1 + k0);
        bf16x8 bv2 = *(const bf16x8*)(Bt + gb2 + k0);
        if (k0) __syncthreads();
        *(bf16x8*)(As + ssl1) = av1;
        *(bf16x8*)(As + ssl2) = av2;
        *(bf16x8*)(Bs + ssl1) = bv1;
        *(bf16x8*)(Bs + ssl2) = bv2;
        __syncthreads();
        bf16x8 af[4], bfr[4];
#pragma unroll
        for (int f = 0; f < 4; ++f) {
            int ar = wr * 64 + f * 16 + rr;
            int br = wc * 64 + f * 16 + rr;
            af[f]  = *(const bf16x8*)(As + ar * 32 + ((kc ^ ((ar >> 1) & 3)) * 8));
            bfr[f] = *(const bf16x8*)(Bs + br * 32 + ((kc ^ ((br >> 1) & 3)) * 8));
        }
#pragma unroll
        for (int fm = 0; fm < 4; ++fm)
#pragma unroll
            for (int fn = 0; fn < 4; ++fn)
                acc[fm][fn] = __builtin_amdgcn_mfma_f32_16x16x32_bf16(af[fm], bfr[fn], acc[fm][fn], 0, 0, 0);
    }
    const int crow0 = m0 + wr * 64 + (lane >> 4) * 4;
    const int ccol0 = n0 + wc * 64 + (lane & 15);
#pragma unroll
    for (int fm = 0; fm < 4; ++fm) {
#pragma unroll
        for (int r = 0; r < 4; ++r) {
            int m = crow0 + fm * 16 + r;
            if (m >= NNODES) continue;
#pragma unroll
            for (int fn = 0; fn < 4; ++fn)
                C[(size_t)m * 256 + ccol0 + fn * 16] = f2bf(acc[fm][fn][r]);
        }
    }
}

// GEMM3: C[M x 40](bf16) = A[M x 256](bf16) @ W[256 x 40](f32), one wave per row
__global__ void k_gemm3(const uint* __restrict__ A, const float* __restrict__ W,
                        ushort* __restrict__ C) {
    __shared__ float aS[4][256];
    int m0 = blockIdx.x * 4;
    int t = threadIdx.x;
    for (int j = t; j < 512; j += 256) {   // uint (bf16-pair) index over 4 rows
        int r = j >> 7, kk = j & 127;
        uint u = A[(size_t)(m0 + r) * 128 + kk];
        aS[r][2*kk] = bflo(u); aS[r][2*kk+1] = bfhi(u);
    }
    __syncthreads();
    int w = t >> 6, lane = t & 63;
    if (lane >= 40) return;
    float acc0 = 0.f, acc1 = 0.f;
#pragma unroll 8
    for (int k = 0; k < 256; k += 2) {
        acc0 = fmaf(aS[w][k],     W[k * 40 + lane],       acc0);
        acc1 = fmaf(aS[w][k + 1], W[(k + 1) * 40 + lane], acc1);
    }
    C[(size_t)(m0 + w) * 40 + lane] = f2bf(acc0 + acc1);
}

// ---------------- BatchNorm ----------------

// bf16 input: thread owns channel-pair p over half the block's rows
__global__ void k_bnstats_bf(const uint* __restrict__ H, float* __restrict__ sums) {
    int t = threadIdx.x;
    int pp = t & 127, half = t >> 7;
    size_t row0 = (size_t)blockIdx.x * 256 + half * 128;
    float s0=0, s20=0, s1=0, s21=0;
    for (int i = 0; i < 128; ++i) {
        size_t m = row0 + i;
        if (m >= NNODES) break;
        uint u = H[m * 128 + pp];
        float v0 = bflo(u), v1 = bfhi(u);
        s0 += v0; s20 += v0*v0; s1 += v1; s21 += v1*v1;
    }
    atomicAdd(&sums[2*pp],       s0);
    atomicAdd(&sums[2*pp+1],     s1);
    atomicAdd(&sums[256+2*pp],   s20);
    atomicAdd(&sums[256+2*pp+1], s21);
}

__global__ void k_bnstats_f(const float* __restrict__ H, float* __restrict__ sums) {
    int c = threadIdx.x;
    size_t r0 = (size_t)blockIdx.x * 256;
    float s = 0.f, s2 = 0.f;
    for (int i = 0; i < 256; ++i) {
        size_t m = r0 + i;
        if (m >= NNODES) break;
        float v = H[m * 256 + c];
        s += v; s2 += v * v;
    }
    atomicAdd(&sums[c], s);
    atomicAdd(&sums[256 + c], s2);
}

__global__ void k_bnfin(const float* __restrict__ sums, const float* __restrict__ g,
                        const float* __restrict__ be, float* __restrict__ scsh) {
    int c = threadIdx.x;
    float mean = sums[c] * (1.0f / NNODES);
    float var  = sums[256 + c] * (1.0f / NNODES) - mean * mean;
    float sc = g[c] * rsqrtf(var + BN_EPS);
    scsh[c] = sc;
    scsh[256 + c] = be[c] - mean * sc;
}

// bf16 in -> bf16 out
__global__ void k_bnrelu_bf(const uint* __restrict__ H, const float* __restrict__ scsh,
                            uint* __restrict__ O) {
    size_t i = (size_t)blockIdx.x * 256 + threadIdx.x;   // uint index, N*128 total
    int pp = (int)(i & 127);
    uint u = H[i];
    float v0 = fmaxf(fmaf(bflo(u), scsh[2*pp],   scsh[256+2*pp]),   0.f);
    float v1 = fmaxf(fmaf(bfhi(u), scsh[2*pp+1], scsh[256+2*pp+1]), 0.f);
    O[i] = (uint)f2bf(v0) | ((uint)f2bf(v1) << 16);
}

// f32 in -> bf16 out
__global__ void k_bnrelu_f2b(const float2* __restrict__ H, const float* __restrict__ scsh,
                             uint* __restrict__ O) {
    size_t i = (size_t)blockIdx.x * 256 + threadIdx.x;   // float2 index, N*128 total
    int pp = (int)(i & 127);
    float2 v = H[i];
    float v0 = fmaxf(fmaf(v.x, scsh[2*pp],   scsh[256+2*pp]),   0.f);
    float v1 = fmaxf(fmaf(v.y, scsh[2*pp+1], scsh[256+2*pp+1]), 0.f);
    O[i] = (uint)f2bf(v0) | ((uint)f2bf(v1) << 16);
}

// ---------------- log_softmax over 40 classes ----------------

__global__ void k_lsm(const float* __restrict__ H, float* __restrict__ out) {
    int t = threadIdx.x;
    int w = t >> 6, lane = t & 63;
    int m = blockIdx.x * 4 + w;
    if (m >= NNODES) return;
    float v = (lane < 40) ? H[(size_t)m * 40 + lane] : -INFINITY;
    float mx = v;
    for (int o = 32; o > 0; o >>= 1) mx = fmaxf(mx, __shfl_xor(mx, o));
    float e = (lane < 40) ? expf(v - mx) : 0.f;
    float s = e;
    for (int o = 32; o > 0; o >>= 1) s += __shfl_xor(s, o);
    if (lane < 40) out[(size_t)m * 40 + lane] = v - mx - logf(s);
}

// ---------------- launch ----------------

extern "C" void kernel_launch(void* const* d_in, const int* in_sizes, int n_in,
                              void* d_out, int out_size, void* d_ws, size_t ws_size,
                              hipStream_t stream) {
    const float* x  = (const float*)d_in[0];
    const int*   ei = (const int*)d_in[1];
    const float* W1 = (const float*)d_in[2];
    const float* W2 = (const float*)d_in[4];
    const float* W3 = (const float*)d_in[6];
    const float* b3 = (const float*)d_in[7];
    const float* g1 = (const float*)d_in[8];
    const float* be1 = (const float*)d_in[9];
    const float* g2 = (const float*)d_in[10];
    const float* be2 = (const float*)d_in[11];
    float* out = (float*)d_out;
    // b1, b2 cancel exactly through BatchNorm (per-channel shift); dropped.

    const int* esrc = ei;
    const int* edst = ei + NEDGES;

    char* p = (char*)d_ws;
    auto alloc = [&](size_t bytes) { char* r = p; p += (bytes + 511) & ~(size_t)511; return r; };
    float* dinv     = (float*)alloc((size_t)NNODES * 4);
    int*   cnt      = (int*)  alloc((size_t)NNODES * 4);
    int*   rowstart = (int*)  alloc((size_t)(NNODES + 1) * 4);
    int*   cursor   = (int*)  alloc((size_t)NNODES * 4);
    int*   chunksums= (int*)  alloc((size_t)NCH * 4);
    float* stats    = (float*)alloc((size_t)2048 * 4);
    ushort* W1t     = (ushort*)alloc((size_t)256 * 128 * 2);
    ushort* W2t     = (ushort*)alloc((size_t)256 * 256 * 2);
    int2*  pairs    = (int2*) alloc((size_t)NEDGES * 8);
    char*  R1       = alloc((size_t)NNODES * 256 * 2);   // 51.2 MB
    char*  R2       = alloc((size_t)NNODES * 256 * 2);   // 51.2 MB
    char*  R3       = alloc((size_t)NNODES * 256 * 4);   // 102.4 MB

    // R1 timeline: xbf16(25.6)+P_bf(25.6) -> a1_bf(51.2) -> t3_bf(8) + h3(16 @ +25.6)
    ushort* xbf16 = (ushort*)R1;
    ushort* P_bf  = (ushort*)R1 + (size_t)NNODES * 128;
    ushort* a1_bf = (ushort*)R1;
    ushort* t3_bf = (ushort*)R1;
    float*  h3    = (float*)(R1 + (size_t)NNODES * 128 * 2);
    // R2 timeline: h1_bf -> t_bf -> a2_bf
    ushort* h1_bf = (ushort*)R2;
    ushort* t_bf  = (ushort*)R2;
    ushort* a2_bf = (ushort*)R2;
    // R3: h2 fp32
    float*  h2    = (float*)R3;

    float* sums1 = stats;        float* scsh1 = stats + 512;
    float* sums2 = stats + 1024; float* scsh2 = stats + 1536;

    hipMemsetAsync(cnt, 0, (size_t)NNODES * 4, stream);
    hipMemsetAsync(stats, 0, (size_t)2048 * 4, stream);

    const int EB = NEDGES / 256;
    const int NB = NCH;

    // CSR build
    k_hist<<<EB, 256, 0, stream>>>(edst, cnt);
    k_dinv<<<NB, 256, 0, stream>>>(cnt, dinv);
    k_chunksum<<<NB, 256, 0, stream>>>(cnt, chunksums);
    k_scan1<<<1, 1, 0, stream>>>(chunksums, rowstart);
    k_scan2<<<NB, 256, 0, stream>>>(cnt, chunksums, rowstart, cursor);
    k_scatter<<<EB, 256, 0, stream>>>(esrc, edst, dinv, cursor, pairs);

    // weight converts + x convert
    k_wconv<<<256, 256, 0, stream>>>(W1, W1t, 128);
    k_wconv<<<256, 256, 0, stream>>>(W2, W2t, 256);
    k_xtobf16<<<NNODES * 128 / 4 / 256, 256, 0, stream>>>(x, xbf16);

    dim3 ggrid((NNODES + 127) / 128, 2);

    // Layer 1
    k_aggb<128, true><<<NNODES / 4, 256, 0, stream>>>(xbf16, P_bf, pairs, rowstart, dinv, nullptr);
    k_gmm<128><<<ggrid, 256, 0, stream>>>(P_bf, W1t, h1_bf);
    k_bnstats_bf<<<NB, 256, 0, stream>>>((const uint*)h1_bf, sums1);
    k_bnfin<<<1, 256, 0, stream>>>(sums1, g1, be1, scsh1);
    k_bnrelu_bf<<<NNODES * 128 / 256, 256, 0, stream>>>((const uint*)h1_bf, scsh1, (uint*)a1_bf);

    // Layer 2
    k_gmm<256><<<ggrid, 256, 0, stream>>>(a1_bf, W2t, t_bf);
    k_aggb<256, false><<<NNODES / 4, 256, 0, stream>>>(t_bf, h2, pairs, rowstart, dinv, nullptr);
    k_bnstats_f<<<NB, 256, 0, stream>>>(h2, sums2);
    k_bnfin<<<1, 256, 0, stream>>>(sums2, g2, be2, scsh2);
    k_bnrelu_f2b<<<NNODES * 128 / 256, 256, 0, stream>>>((const float2*)h2, scsh2, (uint*)a2_bf);

    // Layer 3
    k_gemm3<<<NNODES / 4, 256, 0, stream>>>((const uint*)a2_bf, W3, t3_bf);
    k_agg40b<<<NNODES / 4, 256, 0, stream>>>(t3_bf, h3, pairs, rowstart, dinv, b3);
    k_lsm<<<NNODES / 4, 256, 0, stream>>>(h3, out);
}

// Round 5
// 1126.451 us; speedup vs baseline: 1.9984x; 1.1121x over previous
//
#include <hip/hip_runtime.h>
#include <hip/hip_bf16.h>
#include <math.h>

#define NNODES 100000
#define NEDGES 3200000
#define BN_EPS 1e-5f
#define NCH 391   // ceil(NNODES/256)

typedef unsigned int uint;
typedef unsigned short ushort;
typedef __attribute__((ext_vector_type(8))) short bf16x8;
typedef __attribute__((ext_vector_type(4))) float f32x4;

__device__ inline float bflo(uint u) { return __uint_as_float(u << 16); }
__device__ inline float bfhi(uint u) { return __uint_as_float(u & 0xffff0000u); }
__device__ inline ushort f2bf(float f) {
    __hip_bfloat16 h = __float2bfloat16(f);
    union { __hip_bfloat16 b; ushort u; } c; c.b = h; return c.u;
}

// ---------------- CSR build (edge_index arrives as int32) ----------------

__global__ void k_hist(const int* __restrict__ dst, int* __restrict__ cnt) {
    int e = blockIdx.x * 256 + threadIdx.x;
    if (e < NEDGES) atomicAdd(&cnt[dst[e]], 1);
}

// dinv + per-chunk sum in one pass
__global__ void k_deg(const int* __restrict__ cnt, float* __restrict__ dinv,
                      int* __restrict__ chunksums) {
    __shared__ int s[256];
    int i = blockIdx.x * 256 + threadIdx.x;
    int c = (i < NNODES) ? cnt[i] : 0;
    if (i < NNODES) dinv[i] = rsqrtf((float)c + 1.0f);   // deg includes self-loop
    s[threadIdx.x] = c;
    __syncthreads();
    for (int o = 128; o > 0; o >>= 1) {
        if (threadIdx.x < o) s[threadIdx.x] += s[threadIdx.x + o];
        __syncthreads();
    }
    if (threadIdx.x == 0) chunksums[blockIdx.x] = s[0];
}

// parallel exclusive scan over NCH chunk sums (one block of 512)
__global__ void k_scan1(int* __restrict__ chunksums, int* __restrict__ rowstart) {
    __shared__ int s[512];
    int t = threadIdx.x;
    int v = (t < NCH) ? chunksums[t] : 0;
    s[t] = v;
    __syncthreads();
    for (int o = 1; o < 512; o <<= 1) {
        int add = (t >= o) ? s[t - o] : 0;
        __syncthreads();
        s[t] += add;
        __syncthreads();
    }
    if (t < NCH) chunksums[t] = s[t] - v;           // exclusive
    if (t == NCH - 1) rowstart[NNODES] = s[t];      // total == NEDGES
}

__global__ void k_scan2(const int* __restrict__ cnt, const int* __restrict__ chunkbase,
                        int* __restrict__ rowstart, int* __restrict__ cursor) {
    __shared__ int s[256];
    int t = threadIdx.x;
    int i = blockIdx.x * 256 + t;
    int v = (i < NNODES) ? cnt[i] : 0;
    s[t] = v;
    __syncthreads();
    for (int o = 1; o < 256; o <<= 1) {
        int add = (t >= o) ? s[t - o] : 0;
        __syncthreads();
        s[t] += add;
        __syncthreads();
    }
    if (i < NNODES) {
        int excl = s[t] - v + chunkbase[blockIdx.x];
        rowstart[i] = excl;
        cursor[i]   = excl;
    }
}

__global__ void k_scatter(const int* __restrict__ src, const int* __restrict__ dst,
                          const float* __restrict__ dinv, int* __restrict__ cursor,
                          int2* __restrict__ pairs) {
    int e = blockIdx.x * 256 + threadIdx.x;
    if (e >= NEDGES) return;
    int s = src[e], d = dst[e];
    int p = atomicAdd(&cursor[d], 1);
    float w = dinv[s] * dinv[d];
    pairs[p] = make_int2(s, __float_as_int(w));
}

// ---------------- bf16 aggregation, one wave per node, 8 gathers in flight ----------------

template <int F, bool BF16OUT>
__global__ __launch_bounds__(256) void k_aggb(
    const ushort* __restrict__ X, void* __restrict__ Yv,
    const int2* __restrict__ pairs, const int* __restrict__ rowstart,
    const float* __restrict__ dinv, const float* __restrict__ bias) {
    constexpr int VEC = F / 64;   // 2 or 4
    constexpr int NU  = VEC / 2;  // uints per lane (1 or 2)
    const int sub = threadIdx.x >> 6;
    const int t   = threadIdx.x & 63;
    const int d   = blockIdx.x * 4 + sub;
    if (d >= NNODES) return;
    const int r0 = rowstart[d], r1 = rowstart[d + 1];
    const size_t cb = (size_t)VEC * t;
    float acc[VEC] = {};
    int p = r0;
    for (; p + 8 <= r1; p += 8) {
        int2 e[8];
#pragma unroll
        for (int j = 0; j < 8; ++j) e[j] = pairs[p + j];
        if constexpr (NU == 2) {
            uint2 u[8];
#pragma unroll
            for (int j = 0; j < 8; ++j) u[j] = *(const uint2*)(X + (size_t)e[j].x * F + cb);
#pragma unroll
            for (int j = 0; j < 8; ++j) {
                float w = __int_as_float(e[j].y);
                acc[0]=fmaf(w,bflo(u[j].x),acc[0]); acc[1]=fmaf(w,bfhi(u[j].x),acc[1]);
                acc[2]=fmaf(w,bflo(u[j].y),acc[2]); acc[3]=fmaf(w,bfhi(u[j].y),acc[3]);
            }
        } else {
            uint u[8];
#pragma unroll
            for (int j = 0; j < 8; ++j) u[j] = *(const uint*)(X + (size_t)e[j].x * F + cb);
#pragma unroll
            for (int j = 0; j < 8; ++j) {
                float w = __int_as_float(e[j].y);
                acc[0]=fmaf(w,bflo(u[j]),acc[0]); acc[1]=fmaf(w,bfhi(u[j]),acc[1]);
            }
        }
    }
    for (; p < r1; ++p) {
        int2 e = pairs[p];
        float w = __int_as_float(e.y);
        if constexpr (NU == 2) {
            uint2 u = *(const uint2*)(X + (size_t)e.x * F + cb);
            acc[0]=fmaf(w,bflo(u.x),acc[0]); acc[1]=fmaf(w,bfhi(u.x),acc[1]);
            acc[2]=fmaf(w,bflo(u.y),acc[2]); acc[3]=fmaf(w,bfhi(u.y),acc[3]);
        } else {
            uint u = *(const uint*)(X + (size_t)e.x * F + cb);
            acc[0]=fmaf(w,bflo(u),acc[0]); acc[1]=fmaf(w,bfhi(u),acc[1]);
        }
    }
    float di = dinv[d], ws = di * di;
    if constexpr (NU == 2) {
        uint2 u = *(const uint2*)(X + (size_t)d * F + cb);
        acc[0]=fmaf(ws,bflo(u.x),acc[0]); acc[1]=fmaf(ws,bfhi(u.x),acc[1]);
        acc[2]=fmaf(ws,bflo(u.y),acc[2]); acc[3]=fmaf(ws,bfhi(u.y),acc[3]);
    } else {
        uint u = *(const uint*)(X + (size_t)d * F + cb);
        acc[0]=fmaf(ws,bflo(u),acc[0]); acc[1]=fmaf(ws,bfhi(u),acc[1]);
    }
    if (bias) {
#pragma unroll
        for (int j = 0; j < VEC; ++j) acc[j] += bias[cb + j];
    }
    if constexpr (BF16OUT) {
        uint* Y = (uint*)Yv;
        uint o0 = (uint)f2bf(acc[0]) | ((uint)f2bf(acc[1]) << 16);
        if constexpr (NU == 2) {
            uint o1 = (uint)f2bf(acc[2]) | ((uint)f2bf(acc[3]) << 16);
            *(uint2*)(Y + (size_t)d * (F/2) + cb/2) = make_uint2(o0, o1);
        } else {
            Y[(size_t)d * (F/2) + cb/2] = o0;
        }
    } else {
        float* Y = (float*)Yv;
        if constexpr (NU == 2) {
            float4 o; o.x=acc[0]; o.y=acc[1]; o.z=acc[2]; o.w=acc[3];
            *(float4*)(Y + (size_t)d * F + cb) = o;
        } else {
            *(float2*)(Y + (size_t)d * F + cb) = make_float2(acc[0], acc[1]);
        }
    }
}

// ---------------- fused 40-wide aggregation + bias + log_softmax ----------------
// 2 nodes per wave (32-lane groups), lanes l32<20 own channel pairs.

__global__ __launch_bounds__(256) void k_agg40lsm(
    const ushort* __restrict__ X, float* __restrict__ out,
    const int2* __restrict__ pairs, const int* __restrict__ rowstart,
    const float* __restrict__ dinv, const float* __restrict__ bias) {
    int t = threadIdx.x;
    int wid = t >> 6, lane = t & 63;
    int sub = lane >> 5, l32 = lane & 31;
    int d = blockIdx.x * 8 + wid * 2 + sub;    // 12500*8 == NNODES exactly
    bool act = l32 < 20;
    int col = act ? 2 * l32 : 0;               // clamp keeps loads in-row
    const int r0 = rowstart[d], r1 = rowstart[d + 1];
    float a0 = 0.f, a1 = 0.f;
    int p = r0;
    for (; p + 4 <= r1; p += 4) {
        int2 e0 = pairs[p], e1 = pairs[p+1], e2 = pairs[p+2], e3 = pairs[p+3];
        uint u0 = *(const uint*)(X + (size_t)e0.x * 40 + col);
        uint u1 = *(const uint*)(X + (size_t)e1.x * 40 + col);
        uint u2 = *(const uint*)(X + (size_t)e2.x * 40 + col);
        uint u3 = *(const uint*)(X + (size_t)e3.x * 40 + col);
        float w0 = __int_as_float(e0.y), w1 = __int_as_float(e1.y);
        float w2 = __int_as_float(e2.y), w3 = __int_as_float(e3.y);
        a0=fmaf(w0,bflo(u0),a0); a1=fmaf(w0,bfhi(u0),a1);
        a0=fmaf(w1,bflo(u1),a0); a1=fmaf(w1,bfhi(u1),a1);
        a0=fmaf(w2,bflo(u2),a0); a1=fmaf(w2,bfhi(u2),a1);
        a0=fmaf(w3,bflo(u3),a0); a1=fmaf(w3,bfhi(u3),a1);
    }
    for (; p < r1; ++p) {
        int2 e = pairs[p];
        uint u = *(const uint*)(X + (size_t)e.x * 40 + col);
        float w_ = __int_as_float(e.y);
        a0=fmaf(w_,bflo(u),a0); a1=fmaf(w_,bfhi(u),a1);
    }
    float di = dinv[d], ws = di * di;
    uint us = *(const uint*)(X + (size_t)d * 40 + col);
    a0=fmaf(ws,bflo(us),a0); a1=fmaf(ws,bfhi(us),a1);
    if (act) { a0 += bias[col]; a1 += bias[col + 1]; }
    else     { a0 = -INFINITY;  a1 = -INFINITY; }
    // log_softmax across the 40 values held by this 32-lane group
    float mx = fmaxf(a0, a1);
    for (int o = 16; o > 0; o >>= 1) mx = fmaxf(mx, __shfl_xor(mx, o, 32));
    float e = act ? (expf(a0 - mx) + expf(a1 - mx)) : 0.f;
    float s = e;
    for (int o = 16; o > 0; o >>= 1) s += __shfl_xor(s, o, 32);
    float ls = logf(s);
    if (act)
        *(float2*)(out + (size_t)d * 40 + col) = make_float2(a0 - mx - ls, a1 - mx - ls);
}

// ---------------- converts ----------------

__global__ void k_xtobf16(const float* __restrict__ X, ushort* __restrict__ O) {
    int i = blockIdx.x * 256 + threadIdx.x;
    float4 v = ((const float4*)X)[i];
    ushort4 o; o.x=f2bf(v.x); o.y=f2bf(v.y); o.z=f2bf(v.z); o.w=f2bf(v.w);
    ((ushort4*)O)[i] = o;
}

// W [K][256] f32 -> Wt [256][K] bf16
__global__ void k_wconv(const float* __restrict__ W, ushort* __restrict__ Wt, int K) {
    int n = blockIdx.x;
    for (int k = threadIdx.x; k < K; k += 256)
        Wt[n * K + k] = f2bf(W[(size_t)k * 256 + n]);
}

// ---------------- MFMA GEMM: C[M x 256](bf16) = A[M x K](bf16) @ Bt[256 x K]^T ----------------
// Optional fused BN+ReLU applied to A elements during staging (channel = k index).

__device__ inline bf16x8 bnrelu8(bf16x8 v, const float* __restrict__ scsh, int ch) {
    bf16x8 r;
#pragma unroll
    for (int j = 0; j < 8; ++j) {
        float f = __uint_as_float(((uint)(ushort)v[j]) << 16);
        f = fmaxf(fmaf(f, scsh[ch + j], scsh[256 + ch + j]), 0.f);
        r[j] = (short)f2bf(f);
    }
    return r;
}

template <int K, bool BNA>
__global__ __launch_bounds__(256) void k_gmm(
    const ushort* __restrict__ A, const ushort* __restrict__ Bt,
    const float* __restrict__ scsh, ushort* __restrict__ C) {
    __shared__ ushort As[128 * 32];
    __shared__ ushort Bs[128 * 32];
    const int m0 = blockIdx.x * 128;
    const int n0 = blockIdx.y * 128;
    const int tid = threadIdx.x;
    const int lane = tid & 63;
    const int wid = tid >> 6;
    const int wr = wid >> 1, wc = wid & 1;
    const int sr1 = tid >> 2, sc = tid & 3;
    const int sr2 = sr1 + 64;
    const int ssl1 = sr1 * 32 + ((sc ^ ((sr1 >> 1) & 3)) * 8);
    const int ssl2 = sr2 * 32 + ((sc ^ ((sr2 >> 1) & 3)) * 8);
    const size_t ga1 = (size_t)min(m0 + sr1, NNODES - 1) * K + sc * 8;
    const size_t ga2 = (size_t)min(m0 + sr2, NNODES - 1) * K + sc * 8;
    const size_t gb1 = (size_t)(n0 + sr1) * K + sc * 8;
    const size_t gb2 = (size_t)(n0 + sr2) * K + sc * 8;
    const int kc = lane >> 4, rr = lane & 15;
    f32x4 acc[4][4] = {};
    for (int k0 = 0; k0 < K; k0 += 32) {
        bf16x8 av1 = *(const bf16x8*)(A + ga1 + k0);
        bf16x8 av2 = *(const bf16x8*)(A + ga2 + k0);
        bf16x8 bv1 = *(const bf16x8*)(Bt + gb1 + k0);
        bf16x8 bv2 = *(const bf16x8*)(Bt + gb2 + k0);
        if constexpr (BNA) {
            int ch = k0 + sc * 8;
            av1 = bnrelu8(av1, scsh, ch);
            av2 = bnrelu8(av2, scsh, ch);
        }
        if (k0) __syncthreads();
        *(bf16x8*)(As + ssl1) = av1;
        *(bf16x8*)(As + ssl2) = av2;
        *(bf16x8*)(Bs + ssl1) = bv1;
        *(bf16x8*)(Bs + ssl2) = bv2;
        __syncthreads();
        bf16x8 af[4], bfr[4];
#pragma unroll
        for (int f = 0; f < 4; ++f) {
            int ar = wr * 64 + f * 16 + rr;
            int br = wc * 64 + f * 16 + rr;
            af[f]  = *(const bf16x8*)(As + ar * 32 + ((kc ^ ((ar >> 1) & 3)) * 8));
            bfr[f] = *(const bf16x8*)(Bs + br * 32 + ((kc ^ ((br >> 1) & 3)) * 8));
        }
#pragma unroll
        for (int fm = 0; fm < 4; ++fm)
#pragma unroll
            for (int fn = 0; fn < 4; ++fn)
                acc[fm][fn] = __builtin_amdgcn_mfma_f32_16x16x32_bf16(af[fm], bfr[fn], acc[fm][fn], 0, 0, 0);
    }
    const int crow0 = m0 + wr * 64 + (lane >> 4) * 4;
    const int ccol0 = n0 + wc * 64 + (lane & 15);
#pragma unroll
    for (int fm = 0; fm < 4; ++fm) {
#pragma unroll
        for (int r = 0; r < 4; ++r) {
            int m = crow0 + fm * 16 + r;
            if (m >= NNODES) continue;
#pragma unroll
            for (int fn = 0; fn < 4; ++fn)
                C[(size_t)m * 256 + ccol0 + fn * 16] = f2bf(acc[fm][fn][r]);
        }
    }
}

// GEMM3 with fused BN+ReLU on A: C[M x 40](bf16) = relu(bn(A))[M x 256] @ W[256 x 40]
__global__ void k_gemm3(const uint* __restrict__ A, const float* __restrict__ scsh,
                        const float* __restrict__ W, ushort* __restrict__ C) {
    __shared__ float aS[4][256];
    int m0 = blockIdx.x * 4;
    int t = threadIdx.x;
    for (int j = t; j < 512; j += 256) {
        int r = j >> 7, kk = j & 127;
        uint u = A[(size_t)(m0 + r) * 128 + kk];
        aS[r][2*kk]   = fmaxf(fmaf(bflo(u), scsh[2*kk],   scsh[256+2*kk]),   0.f);
        aS[r][2*kk+1] = fmaxf(fmaf(bfhi(u), scsh[2*kk+1], scsh[256+2*kk+1]), 0.f);
    }
    __syncthreads();
    int w = t >> 6, lane = t & 63;
    if (lane >= 40) return;
    float acc0 = 0.f, acc1 = 0.f;
#pragma unroll 8
    for (int k = 0; k < 256; k += 2) {
        acc0 = fmaf(aS[w][k],     W[k * 40 + lane],       acc0);
        acc1 = fmaf(aS[w][k + 1], W[(k + 1) * 40 + lane], acc1);
    }
    C[(size_t)(m0 + w) * 40 + lane] = f2bf(acc0 + acc1);
}

// ---------------- BatchNorm stats (bf16 input) ----------------

__global__ void k_bnstats_bf(const uint* __restrict__ H, float* __restrict__ sums) {
    int t = threadIdx.x;
    int pp = t & 127, half = t >> 7;
    size_t row0 = (size_t)blockIdx.x * 256 + half * 128;
    float s0=0, s20=0, s1=0, s21=0;
    for (int i = 0; i < 128; ++i) {
        size_t m = row0 + i;
        if (m >= NNODES) break;
        uint u = H[m * 128 + pp];
        float v0 = bflo(u), v1 = bfhi(u);
        s0 += v0; s20 += v0*v0; s1 += v1; s21 += v1*v1;
    }
    atomicAdd(&sums[2*pp],       s0);
    atomicAdd(&sums[2*pp+1],     s1);
    atomicAdd(&sums[256+2*pp],   s20);
    atomicAdd(&sums[256+2*pp+1], s21);
}

__global__ void k_bnfin(const float* __restrict__ sums, const float* __restrict__ g,
                        const float* __restrict__ be, float* __restrict__ scsh) {
    int c = threadIdx.x;
    float mean = sums[c] * (1.0f / NNODES);
    float var  = sums[256 + c] * (1.0f / NNODES) - mean * mean;
    float sc = g[c] * rsqrtf(var + BN_EPS);
    scsh[c] = sc;
    scsh[256 + c] = be[c] - mean * sc;
}

// ---------------- launch ----------------

extern "C" void kernel_launch(void* const* d_in, const int* in_sizes, int n_in,
                              void* d_out, int out_size, void* d_ws, size_t ws_size,
                              hipStream_t stream) {
    const float* x  = (const float*)d_in[0];
    const int*   ei = (const int*)d_in[1];
    const float* W1 = (const float*)d_in[2];
    const float* W2 = (const float*)d_in[4];
    const float* W3 = (const float*)d_in[6];
    const float* b3 = (const float*)d_in[7];
    const float* g1 = (const float*)d_in[8];
    const float* be1 = (const float*)d_in[9];
    const float* g2 = (const float*)d_in[10];
    const float* be2 = (const float*)d_in[11];
    float* out = (float*)d_out;
    // b1, b2 cancel exactly through BatchNorm (per-channel shift); dropped.

    const int* esrc = ei;
    const int* edst = ei + NEDGES;

    char* p = (char*)d_ws;
    auto alloc = [&](size_t bytes) { char* r = p; p += (bytes + 511) & ~(size_t)511; return r; };
    float* dinv     = (float*)alloc((size_t)NNODES * 4);
    int*   cnt      = (int*)  alloc((size_t)NNODES * 4);
    int*   rowstart = (int*)  alloc((size_t)(NNODES + 1) * 4);
    int*   cursor   = (int*)  alloc((size_t)NNODES * 4);
    int*   chunksums= (int*)  alloc((size_t)NCH * 4);
    float* stats    = (float*)alloc((size_t)2048 * 4);
    ushort* W1t     = (ushort*)alloc((size_t)256 * 128 * 2);
    ushort* W2t     = (ushort*)alloc((size_t)256 * 256 * 2);
    int2*  pairs    = (int2*) alloc((size_t)NEDGES * 8);
    char*  R1       = alloc((size_t)NNODES * 256 * 2);   // 51.2 MB
    char*  R2       = alloc((size_t)NNODES * 256 * 2);   // 51.2 MB
    char*  R3       = alloc((size_t)NNODES * 256 * 2);   // 51.2 MB

    // R1: xbf16 [0,25.6M) + P_bf [25.6M,51.2M); later t3_bf [0,8M)
    ushort* xbf16 = (ushort*)R1;
    ushort* P_bf  = (ushort*)R1 + (size_t)NNODES * 128;
    ushort* t3_bf = (ushort*)R1;
    // R2: h1_bf (live until gmm256 reads it); later h2_bf
    ushort* h1_bf = (ushort*)R2;
    ushort* h2_bf = (ushort*)R2;
    // R3: t_bf (gmm256 output — MUST be distinct from h1_bf: by-blocks re-read A rows)
    ushort* t_bf  = (ushort*)R3;

    float* sums1 = stats;        float* scsh1 = stats + 512;
    float* sums2 = stats + 1024; float* scsh2 = stats + 1536;

    hipMemsetAsync(cnt, 0, (size_t)NNODES * 4, stream);
    hipMemsetAsync(stats, 0, (size_t)2048 * 4, stream);

    const int EB = NEDGES / 256;
    const int NB = NCH;

    // CSR build
    k_hist<<<EB, 256, 0, stream>>>(edst, cnt);
    k_deg<<<NB, 256, 0, stream>>>(cnt, dinv, chunksums);
    k_scan1<<<1, 512, 0, stream>>>(chunksums, rowstart);
    k_scan2<<<NB, 256, 0, stream>>>(cnt, chunksums, rowstart, cursor);
    k_scatter<<<EB, 256, 0, stream>>>(esrc, edst, dinv, cursor, pairs);

    // converts
    k_wconv<<<256, 256, 0, stream>>>(W1, W1t, 128);
    k_wconv<<<256, 256, 0, stream>>>(W2, W2t, 256);
    k_xtobf16<<<NNODES * 128 / 4 / 256, 256, 0, stream>>>(x, xbf16);

    dim3 ggrid((NNODES + 127) / 128, 2);

    // Layer 1: P = Agg(x); h1 = P@W1; stats(h1)
    k_aggb<128, true><<<NNODES / 4, 256, 0, stream>>>(xbf16, P_bf, pairs, rowstart, dinv, nullptr);
    k_gmm<128, false><<<ggrid, 256, 0, stream>>>(P_bf, W1t, nullptr, h1_bf);
    k_bnstats_bf<<<NB, 256, 0, stream>>>((const uint*)h1_bf, sums1);
    k_bnfin<<<1, 256, 0, stream>>>(sums1, g1, be1, scsh1);

    // Layer 2: t = relu(bn(h1))@W2 (BN fused into A-staging); h2 = Agg(t); stats(h2)
    k_gmm<256, true><<<ggrid, 256, 0, stream>>>(h1_bf, W2t, scsh1, t_bf);
    k_aggb<256, true><<<NNODES / 4, 256, 0, stream>>>(t_bf, h2_bf, pairs, rowstart, dinv, nullptr);
    k_bnstats_bf<<<NB, 256, 0, stream>>>((const uint*)h2_bf, sums2);
    k_bnfin<<<1, 256, 0, stream>>>(sums2, g2, be2, scsh2);

    // Layer 3: t3 = relu(bn(h2))@W3 (fused); out = log_softmax(Agg(t3) + b3) (fused)
    k_gemm3<<<NNODES / 4, 256, 0, stream>>>((const uint*)h2_bf, scsh2, W3, t3_bf);
    k_agg40lsm<<<NNODES / 8, 256, 0, stream>>>(t3_bf, out, pairs, rowstart, dinv, b3);
}

// Round 6
// 942.089 us; speedup vs baseline: 2.3895x; 1.1957x over previous
//
#include <hip/hip_runtime.h>
#include <hip/hip_bf16.h>
#include <math.h>

#define NNODES 100000
#define NEDGES 3200000
#define BN_EPS 1e-5f
#define NCH 391   // ceil(NNODES/256)

typedef unsigned int uint;
typedef unsigned short ushort;
typedef __attribute__((ext_vector_type(8))) short bf16x8;
typedef __attribute__((ext_vector_type(4))) float f32x4;

__device__ inline float bflo(uint u) { return __uint_as_float(u << 16); }
__device__ inline float bfhi(uint u) { return __uint_as_float(u & 0xffff0000u); }
__device__ inline ushort f2bf(float f) {
    __hip_bfloat16 h = __float2bfloat16(f);
    union { __hip_bfloat16 b; ushort u; } c; c.b = h; return c.u;
}

// ---------------- CSR build (edge_index arrives as int32) ----------------

__global__ void k_hist(const int* __restrict__ dst, int* __restrict__ cnt) {
    int e = (blockIdx.x * 256 + threadIdx.x) * 2;
    int2 v = *(const int2*)(dst + e);
    atomicAdd(&cnt[v.x], 1);
    atomicAdd(&cnt[v.y], 1);
}

// dinv + per-chunk sum in one pass
__global__ void k_deg(const int* __restrict__ cnt, float* __restrict__ dinv,
                      int* __restrict__ chunksums) {
    __shared__ int s[256];
    int i = blockIdx.x * 256 + threadIdx.x;
    int c = (i < NNODES) ? cnt[i] : 0;
    if (i < NNODES) dinv[i] = rsqrtf((float)c + 1.0f);   // deg includes self-loop
    s[threadIdx.x] = c;
    __syncthreads();
    for (int o = 128; o > 0; o >>= 1) {
        if (threadIdx.x < o) s[threadIdx.x] += s[threadIdx.x + o];
        __syncthreads();
    }
    if (threadIdx.x == 0) chunksums[blockIdx.x] = s[0];
}

// parallel exclusive scan over NCH chunk sums (one block of 512)
__global__ void k_scan1(int* __restrict__ chunksums, int* __restrict__ rowstart) {
    __shared__ int s[512];
    int t = threadIdx.x;
    int v = (t < NCH) ? chunksums[t] : 0;
    s[t] = v;
    __syncthreads();
    for (int o = 1; o < 512; o <<= 1) {
        int add = (t >= o) ? s[t - o] : 0;
        __syncthreads();
        s[t] += add;
        __syncthreads();
    }
    if (t < NCH) chunksums[t] = s[t] - v;           // exclusive
    if (t == NCH - 1) rowstart[NNODES] = s[t];      // total == NEDGES
}

__global__ void k_scan2(const int* __restrict__ cnt, const int* __restrict__ chunkbase,
                        int* __restrict__ rowstart, int* __restrict__ cursor) {
    __shared__ int s[256];
    int t = threadIdx.x;
    int i = blockIdx.x * 256 + t;
    int v = (i < NNODES) ? cnt[i] : 0;
    s[t] = v;
    __syncthreads();
    for (int o = 1; o < 256; o <<= 1) {
        int add = (t >= o) ? s[t - o] : 0;
        __syncthreads();
        s[t] += add;
        __syncthreads();
    }
    if (i < NNODES) {
        int excl = s[t] - v + chunkbase[blockIdx.x];
        rowstart[i] = excl;
        cursor[i]   = excl;
    }
}

__global__ void k_scatter(const int* __restrict__ src, const int* __restrict__ dst,
                          const float* __restrict__ dinv, int* __restrict__ cursor,
                          int2* __restrict__ pairs) {
    int e = blockIdx.x * 256 + threadIdx.x;
    if (e >= NEDGES) return;
    int s = src[e], d = dst[e];
    int p = atomicAdd(&cursor[d], 1);
    float w = dinv[s] * dinv[d];
    pairs[p] = make_int2(s, __float_as_int(w));
}

// ---------------- half-wave bf16 aggregation ----------------
// One wave per node; each 32-lane half covers a full row (16B/lane for F=256),
// halves process alternating edges -> 2U edges in flight per wave. fp32 accum,
// cross-half shfl reduce, bf16 out.

template <int F, int U>
__global__ __launch_bounds__(256) void k_aggh(
    const ushort* __restrict__ X, ushort* __restrict__ Y,
    const int2* __restrict__ pairs, const int* __restrict__ rowstart,
    const float* __restrict__ dinv) {
    constexpr int CPL = F / 32;   // channels per lane: 8 (F=256) or 4 (F=128)
    const int wv = threadIdx.x >> 6;
    const int lane = threadIdx.x & 63;
    const int h = lane >> 5, l32 = lane & 31;
    const int d = blockIdx.x * 4 + wv;          // grid*4 == NNODES exactly
    const int r0 = rowstart[d], r1 = rowstart[d + 1];
    const ushort* Xb = X + (size_t)CPL * l32;
    float acc[CPL] = {};
    int p = r0;
    for (; p + 2 * U <= r1; p += 2 * U) {
        int2 e[U];
#pragma unroll
        for (int j = 0; j < U; ++j) e[j] = pairs[p + 2 * j + h];
        if constexpr (CPL == 8) {
            uint4 u[U];
#pragma unroll
            for (int j = 0; j < U; ++j) u[j] = *(const uint4*)(Xb + (size_t)e[j].x * F);
#pragma unroll
            for (int j = 0; j < U; ++j) {
                float w = __int_as_float(e[j].y);
                acc[0]=fmaf(w,bflo(u[j].x),acc[0]); acc[1]=fmaf(w,bfhi(u[j].x),acc[1]);
                acc[2]=fmaf(w,bflo(u[j].y),acc[2]); acc[3]=fmaf(w,bfhi(u[j].y),acc[3]);
                acc[4]=fmaf(w,bflo(u[j].z),acc[4]); acc[5]=fmaf(w,bfhi(u[j].z),acc[5]);
                acc[6]=fmaf(w,bflo(u[j].w),acc[6]); acc[7]=fmaf(w,bfhi(u[j].w),acc[7]);
            }
        } else {
            uint2 u[U];
#pragma unroll
            for (int j = 0; j < U; ++j) u[j] = *(const uint2*)(Xb + (size_t)e[j].x * F);
#pragma unroll
            for (int j = 0; j < U; ++j) {
                float w = __int_as_float(e[j].y);
                acc[0]=fmaf(w,bflo(u[j].x),acc[0]); acc[1]=fmaf(w,bfhi(u[j].x),acc[1]);
                acc[2]=fmaf(w,bflo(u[j].y),acc[2]); acc[3]=fmaf(w,bfhi(u[j].y),acc[3]);
            }
        }
    }
    for (; p + 2 <= r1; p += 2) {   // paired tail
        int2 e = pairs[p + h];
        float w = __int_as_float(e.y);
        if constexpr (CPL == 8) {
            uint4 u = *(const uint4*)(Xb + (size_t)e.x * F);
            acc[0]=fmaf(w,bflo(u.x),acc[0]); acc[1]=fmaf(w,bfhi(u.x),acc[1]);
            acc[2]=fmaf(w,bflo(u.y),acc[2]); acc[3]=fmaf(w,bfhi(u.y),acc[3]);
            acc[4]=fmaf(w,bflo(u.z),acc[4]); acc[5]=fmaf(w,bfhi(u.z),acc[5]);
            acc[6]=fmaf(w,bflo(u.w),acc[6]); acc[7]=fmaf(w,bfhi(u.w),acc[7]);
        } else {
            uint2 u = *(const uint2*)(Xb + (size_t)e.x * F);
            acc[0]=fmaf(w,bflo(u.x),acc[0]); acc[1]=fmaf(w,bfhi(u.x),acc[1]);
            acc[2]=fmaf(w,bflo(u.y),acc[2]); acc[3]=fmaf(w,bfhi(u.y),acc[3]);
        }
    }
    if (p < r1 && h == 0) {          // odd final edge
        int2 e = pairs[p];
        float w = __int_as_float(e.y);
        if constexpr (CPL == 8) {
            uint4 u = *(const uint4*)(Xb + (size_t)e.x * F);
            acc[0]=fmaf(w,bflo(u.x),acc[0]); acc[1]=fmaf(w,bfhi(u.x),acc[1]);
            acc[2]=fmaf(w,bflo(u.y),acc[2]); acc[3]=fmaf(w,bfhi(u.y),acc[3]);
            acc[4]=fmaf(w,bflo(u.z),acc[4]); acc[5]=fmaf(w,bfhi(u.z),acc[5]);
            acc[6]=fmaf(w,bflo(u.w),acc[6]); acc[7]=fmaf(w,bfhi(u.w),acc[7]);
        } else {
            uint2 u = *(const uint2*)(Xb + (size_t)e.x * F);
            acc[0]=fmaf(w,bflo(u.x),acc[0]); acc[1]=fmaf(w,bfhi(u.x),acc[1]);
            acc[2]=fmaf(w,bflo(u.y),acc[2]); acc[3]=fmaf(w,bfhi(u.y),acc[3]);
        }
    }
#pragma unroll
    for (int c = 0; c < CPL; ++c) acc[c] += __shfl_xor(acc[c], 32);
    if (h == 0) {
        float di = dinv[d], ws = di * di;
        if constexpr (CPL == 8) {
            uint4 u = *(const uint4*)(Xb + (size_t)d * F);
            acc[0]=fmaf(ws,bflo(u.x),acc[0]); acc[1]=fmaf(ws,bfhi(u.x),acc[1]);
            acc[2]=fmaf(ws,bflo(u.y),acc[2]); acc[3]=fmaf(ws,bfhi(u.y),acc[3]);
            acc[4]=fmaf(ws,bflo(u.z),acc[4]); acc[5]=fmaf(ws,bfhi(u.z),acc[5]);
            acc[6]=fmaf(ws,bflo(u.w),acc[6]); acc[7]=fmaf(ws,bfhi(u.w),acc[7]);
            uint4 o;
            o.x = (uint)f2bf(acc[0]) | ((uint)f2bf(acc[1]) << 16);
            o.y = (uint)f2bf(acc[2]) | ((uint)f2bf(acc[3]) << 16);
            o.z = (uint)f2bf(acc[4]) | ((uint)f2bf(acc[5]) << 16);
            o.w = (uint)f2bf(acc[6]) | ((uint)f2bf(acc[7]) << 16);
            *(uint4*)(Y + (size_t)d * F + CPL * l32) = o;
        } else {
            uint2 u = *(const uint2*)(Xb + (size_t)d * F);
            acc[0]=fmaf(ws,bflo(u.x),acc[0]); acc[1]=fmaf(ws,bfhi(u.x),acc[1]);
            acc[2]=fmaf(ws,bflo(u.y),acc[2]); acc[3]=fmaf(ws,bfhi(u.y),acc[3]);
            uint2 o;
            o.x = (uint)f2bf(acc[0]) | ((uint)f2bf(acc[1]) << 16);
            o.y = (uint)f2bf(acc[2]) | ((uint)f2bf(acc[3]) << 16);
            *(uint2*)(Y + (size_t)d * F + CPL * l32) = o;
        }
    }
}

// ---------------- fused 40-wide aggregation + bias + log_softmax ----------------

__global__ __launch_bounds__(256) void k_agg40lsm(
    const ushort* __restrict__ X, float* __restrict__ out,
    const int2* __restrict__ pairs, const int* __restrict__ rowstart,
    const float* __restrict__ dinv, const float* __restrict__ bias) {
    int t = threadIdx.x;
    int wid = t >> 6, lane = t & 63;
    int sub = lane >> 5, l32 = lane & 31;
    int d = blockIdx.x * 8 + wid * 2 + sub;    // 12500*8 == NNODES exactly
    bool act = l32 < 20;
    int col = act ? 2 * l32 : 0;
    const int r0 = rowstart[d], r1 = rowstart[d + 1];
    float a0 = 0.f, a1 = 0.f;
    int p = r0;
    for (; p + 8 <= r1; p += 8) {
        int2 e[8]; uint u[8];
#pragma unroll
        for (int j = 0; j < 8; ++j) e[j] = pairs[p + j];
#pragma unroll
        for (int j = 0; j < 8; ++j) u[j] = *(const uint*)(X + (size_t)e[j].x * 40 + col);
#pragma unroll
        for (int j = 0; j < 8; ++j) {
            float w = __int_as_float(e[j].y);
            a0 = fmaf(w, bflo(u[j]), a0); a1 = fmaf(w, bfhi(u[j]), a1);
        }
    }
    for (; p < r1; ++p) {
        int2 e = pairs[p];
        uint u = *(const uint*)(X + (size_t)e.x * 40 + col);
        float w_ = __int_as_float(e.y);
        a0 = fmaf(w_, bflo(u), a0); a1 = fmaf(w_, bfhi(u), a1);
    }
    float di = dinv[d], ws = di * di;
    uint us = *(const uint*)(X + (size_t)d * 40 + col);
    a0 = fmaf(ws, bflo(us), a0); a1 = fmaf(ws, bfhi(us), a1);
    if (act) { a0 += bias[col]; a1 += bias[col + 1]; }
    else     { a0 = -INFINITY;  a1 = -INFINITY; }
    float mx = fmaxf(a0, a1);
    for (int o = 16; o > 0; o >>= 1) mx = fmaxf(mx, __shfl_xor(mx, o, 32));
    float e = act ? (expf(a0 - mx) + expf(a1 - mx)) : 0.f;
    float s = e;
    for (int o = 16; o > 0; o >>= 1) s += __shfl_xor(s, o, 32);
    float ls = logf(s);
    if (act)
        *(float2*)(out + (size_t)d * 40 + col) = make_float2(a0 - mx - ls, a1 - mx - ls);
}

// ---------------- converts ----------------

__global__ void k_xtobf16(const float* __restrict__ X, ushort* __restrict__ O) {
    int i = blockIdx.x * 256 + threadIdx.x;
    float4 v = ((const float4*)X)[i];
    ushort4 o; o.x=f2bf(v.x); o.y=f2bf(v.y); o.z=f2bf(v.z); o.w=f2bf(v.w);
    ((ushort4*)O)[i] = o;
}

// All weight transposes in one kernel:
// blocks 0..255: W1t[256][128]; 256..511: W2t[256][256]; 512..559: W3t[48][256] (pad rows 40-47)
__global__ void k_wconv3(const float* __restrict__ W1, const float* __restrict__ W2,
                         const float* __restrict__ W3, ushort* __restrict__ W1t,
                         ushort* __restrict__ W2t, ushort* __restrict__ W3t) {
    int b = blockIdx.x;
    if (b < 256) {
        int n = b;
        for (int k = threadIdx.x; k < 128; k += 256)
            W1t[n * 128 + k] = f2bf(W1[(size_t)k * 256 + n]);
    } else if (b < 512) {
        int n = b - 256;
        for (int k = threadIdx.x; k < 256; k += 256)
            W2t[n * 256 + k] = f2bf(W2[(size_t)k * 256 + n]);
    } else {
        int n = b - 512;
        for (int k = threadIdx.x; k < 256; k += 256)
            W3t[n * 256 + k] = (n < 40) ? f2bf(W3[(size_t)k * 40 + n]) : (ushort)0;
    }
}

// ---------------- MFMA GEMM: C[M x 256](bf16) = A[M x K](bf16) @ Bt[256 x K]^T ----------------
// BNA: fused BN+ReLU on A during staging. STATS: per-channel sum/sumsq of f32 C into sums.

__device__ inline bf16x8 bnrelu8(bf16x8 v, const float* __restrict__ scsh, int ch) {
    bf16x8 r;
#pragma unroll
    for (int j = 0; j < 8; ++j) {
        float f = __uint_as_float(((uint)(ushort)v[j]) << 16);
        f = fmaxf(fmaf(f, scsh[ch + j], scsh[256 + ch + j]), 0.f);
        r[j] = (short)f2bf(f);
    }
    return r;
}

template <int K, bool BNA, bool STATS>
__global__ __launch_bounds__(256) void k_gmm(
    const ushort* __restrict__ A, const ushort* __restrict__ Bt,
    const float* __restrict__ scsh, ushort* __restrict__ C,
    float* __restrict__ sums) {
    __shared__ ushort As[128 * 32];
    __shared__ ushort Bs[128 * 32];
    const int m0 = blockIdx.x * 128;
    const int n0 = blockIdx.y * 128;
    const int tid = threadIdx.x;
    const int lane = tid & 63;
    const int wid = tid >> 6;
    const int wr = wid >> 1, wc = wid & 1;
    const int sr1 = tid >> 2, sc = tid & 3;
    const int sr2 = sr1 + 64;
    const int ssl1 = sr1 * 32 + ((sc ^ ((sr1 >> 1) & 3)) * 8);
    const int ssl2 = sr2 * 32 + ((sc ^ ((sr2 >> 1) & 3)) * 8);
    const size_t ga1 = (size_t)min(m0 + sr1, NNODES - 1) * K + sc * 8;
    const size_t ga2 = (size_t)min(m0 + sr2, NNODES - 1) * K + sc * 8;
    const size_t gb1 = (size_t)(n0 + sr1) * K + sc * 8;
    const size_t gb2 = (size_t)(n0 + sr2) * K + sc * 8;
    const int kc = lane >> 4, rr = lane & 15;
    f32x4 acc[4][4] = {};
    for (int k0 = 0; k0 < K; k0 += 32) {
        bf16x8 av1 = *(const bf16x8*)(A + ga1 + k0);
        bf16x8 av2 = *(const bf16x8*)(A + ga2 + k0);
        bf16x8 bv1 = *(const bf16x8*)(Bt + gb1 + k0);
        bf16x8 bv2 = *(const bf16x8*)(Bt + gb2 + k0);
        if constexpr (BNA) {
            int ch = k0 + sc * 8;
            av1 = bnrelu8(av1, scsh, ch);
            av2 = bnrelu8(av2, scsh, ch);
        }
        if (k0) __syncthreads();
        *(bf16x8*)(As + ssl1) = av1;
        *(bf16x8*)(As + ssl2) = av2;
        *(bf16x8*)(Bs + ssl1) = bv1;
        *(bf16x8*)(Bs + ssl2) = bv2;
        __syncthreads();
        bf16x8 af[4], bfr[4];
#pragma unroll
        for (int f = 0; f < 4; ++f) {
            int ar = wr * 64 + f * 16 + rr;
            int br = wc * 64 + f * 16 + rr;
            af[f]  = *(const bf16x8*)(As + ar * 32 + ((kc ^ ((ar >> 1) & 3)) * 8));
            bfr[f] = *(const bf16x8*)(Bs + br * 32 + ((kc ^ ((br >> 1) & 3)) * 8));
        }
#pragma unroll
        for (int fm = 0; fm < 4; ++fm)
#pragma unroll
            for (int fn = 0; fn < 4; ++fn)
                acc[fm][fn] = __builtin_amdgcn_mfma_f32_16x16x32_bf16(af[fm], bfr[fn], acc[fm][fn], 0, 0, 0);
    }
    const int crow0 = m0 + wr * 64 + (lane >> 4) * 4;
    const int ccol0 = n0 + wc * 64 + (lane & 15);
#pragma unroll
    for (int fm = 0; fm < 4; ++fm) {
#pragma unroll
        for (int r = 0; r < 4; ++r) {
            int m = crow0 + fm * 16 + r;
            if (m >= NNODES) continue;
#pragma unroll
            for (int fn = 0; fn < 4; ++fn)
                C[(size_t)m * 256 + ccol0 + fn * 16] = f2bf(acc[fm][fn][r]);
        }
    }
    if constexpr (STATS) {
#pragma unroll
        for (int fn = 0; fn < 4; ++fn) {
            float s = 0.f, s2 = 0.f;
#pragma unroll
            for (int fm = 0; fm < 4; ++fm)
#pragma unroll
                for (int r = 0; r < 4; ++r) {
                    int m = crow0 + fm * 16 + r;
                    if (m < NNODES) { float v = acc[fm][fn][r]; s += v; s2 += v * v; }
                }
            s  += __shfl_xor(s, 16);  s  += __shfl_xor(s, 32);
            s2 += __shfl_xor(s2, 16); s2 += __shfl_xor(s2, 32);
            if (lane < 16) {
                int ch = ccol0 + fn * 16;
                atomicAdd(&sums[ch], s);
                atomicAdd(&sums[256 + ch], s2);
            }
        }
    }
}

// ---------------- MFMA GEMM3: C[M x 40](bf16) = relu(bn(A))[M x 256] @ W3t[48 x 256]^T ----
// 128x48 tile, 4 waves (each 32 rows x 48 cols), BK=64, BN fused into A staging.

__global__ __launch_bounds__(256) void k_gmm3m(
    const ushort* __restrict__ A, const ushort* __restrict__ Bt,
    const float* __restrict__ scsh, ushort* __restrict__ C) {
    __shared__ ushort As[128 * 64];
    __shared__ ushort Bs[48 * 64];
    const int m0 = blockIdx.x * 128;
    const int tid = threadIdx.x;
    const int lane = tid & 63;
    const int wm = tid >> 6;
    const int kc = lane >> 4, rr = lane & 15;
    f32x4 acc[2][3] = {};
    for (int k0 = 0; k0 < 256; k0 += 64) {
        bf16x8 avs[4];
        int arow[4], ach[4];
#pragma unroll
        for (int i = 0; i < 4; ++i) {
            int c = i * 256 + tid;
            arow[i] = c >> 3; ach[i] = c & 7;
            int m = min(m0 + arow[i], NNODES - 1);
            bf16x8 v = *(const bf16x8*)(A + (size_t)m * 256 + k0 + ach[i] * 8);
            avs[i] = bnrelu8(v, scsh, k0 + ach[i] * 8);
        }
        bf16x8 bvs[2];
#pragma unroll
        for (int i = 0; i < 2; ++i) {
            int c = i * 256 + tid;
            if (c < 384) {
                int row = c >> 3, ch = c & 7;
                bvs[i] = *(const bf16x8*)(Bt + (size_t)row * 256 + k0 + ch * 8);
            }
        }
        if (k0) __syncthreads();
#pragma unroll
        for (int i = 0; i < 4; ++i)
            *(bf16x8*)(As + arow[i] * 64 + ((ach[i] ^ (arow[i] & 7)) * 8)) = avs[i];
#pragma unroll
        for (int i = 0; i < 2; ++i) {
            int c = i * 256 + tid;
            if (c < 384) {
                int row = c >> 3, ch = c & 7;
                *(bf16x8*)(Bs + row * 64 + ((ch ^ (row & 7)) * 8)) = bvs[i];
            }
        }
        __syncthreads();
#pragma unroll
        for (int ks = 0; ks < 2; ++ks) {
            bf16x8 af[2], bfm[3];
#pragma unroll
            for (int fm = 0; fm < 2; ++fm) {
                int ar = wm * 32 + fm * 16 + rr;
                af[fm] = *(const bf16x8*)(As + ar * 64 + (((ks * 4 + kc) ^ (ar & 7)) * 8));
            }
#pragma unroll
            for (int fn = 0; fn < 3; ++fn) {
                int br = fn * 16 + rr;
                bfm[fn] = *(const bf16x8*)(Bs + br * 64 + (((ks * 4 + kc) ^ (br & 7)) * 8));
            }
#pragma unroll
            for (int fm = 0; fm < 2; ++fm)
#pragma unroll
                for (int fn = 0; fn < 3; ++fn)
                    acc[fm][fn] = __builtin_amdgcn_mfma_f32_16x16x32_bf16(af[fm], bfm[fn], acc[fm][fn], 0, 0, 0);
        }
    }
    const int crow0 = m0 + wm * 32 + (lane >> 4) * 4;
    const int ccol = lane & 15;
#pragma unroll
    for (int fm = 0; fm < 2; ++fm)
#pragma unroll
        for (int r = 0; r < 4; ++r) {
            int m = crow0 + fm * 16 + r;
            if (m >= NNODES) continue;
#pragma unroll
            for (int fn = 0; fn < 3; ++fn) {
                int col = fn * 16 + ccol;
                if (col < 40) C[(size_t)m * 40 + col] = f2bf(acc[fm][fn][r]);
            }
        }
}

// ---------------- BatchNorm ----------------

__global__ void k_bnstats_bf(const uint* __restrict__ H, float* __restrict__ sums) {
    int t = threadIdx.x;
    int pp = t & 127, half = t >> 7;
    size_t row0 = (size_t)blockIdx.x * 256 + half * 128;
    float s0=0, s20=0, s1=0, s21=0;
    for (int i = 0; i < 128; ++i) {
        size_t m = row0 + i;
        if (m >= NNODES) break;
        uint u = H[m * 128 + pp];
        float v0 = bflo(u), v1 = bfhi(u);
        s0 += v0; s20 += v0*v0; s1 += v1; s21 += v1*v1;
    }
    atomicAdd(&sums[2*pp],       s0);
    atomicAdd(&sums[2*pp+1],     s1);
    atomicAdd(&sums[256+2*pp],   s20);
    atomicAdd(&sums[256+2*pp+1], s21);
}

__global__ void k_bnfin(const float* __restrict__ sums, const float* __restrict__ g,
                        const float* __restrict__ be, float* __restrict__ scsh) {
    int c = threadIdx.x;
    float mean = sums[c] * (1.0f / NNODES);
    float var  = sums[256 + c] * (1.0f / NNODES) - mean * mean;
    float sc = g[c] * rsqrtf(var + BN_EPS);
    scsh[c] = sc;
    scsh[256 + c] = be[c] - mean * sc;
}

// ---------------- launch ----------------

extern "C" void kernel_launch(void* const* d_in, const int* in_sizes, int n_in,
                              void* d_out, int out_size, void* d_ws, size_t ws_size,
                              hipStream_t stream) {
    const float* x  = (const float*)d_in[0];
    const int*   ei = (const int*)d_in[1];
    const float* W1 = (const float*)d_in[2];
    const float* W2 = (const float*)d_in[4];
    const float* W3 = (const float*)d_in[6];
    const float* b3 = (const float*)d_in[7];
    const float* g1 = (const float*)d_in[8];
    const float* be1 = (const float*)d_in[9];
    const float* g2 = (const float*)d_in[10];
    const float* be2 = (const float*)d_in[11];
    float* out = (float*)d_out;
    // b1, b2 cancel exactly through BatchNorm (per-channel shift); dropped.

    const int* esrc = ei;
    const int* edst = ei + NEDGES;

    char* p = (char*)d_ws;
    auto alloc = [&](size_t bytes) { char* r = p; p += (bytes + 511) & ~(size_t)511; return r; };
    float* dinv     = (float*)alloc((size_t)NNODES * 4);
    int*   cnt      = (int*)  alloc((size_t)NNODES * 4);
    int*   rowstart = (int*)  alloc((size_t)(NNODES + 1) * 4);
    int*   cursor   = (int*)  alloc((size_t)NNODES * 4);
    int*   chunksums= (int*)  alloc((size_t)NCH * 4);
    float* stats    = (float*)alloc((size_t)2048 * 4);
    ushort* W1t     = (ushort*)alloc((size_t)256 * 128 * 2);
    ushort* W2t     = (ushort*)alloc((size_t)256 * 256 * 2);
    ushort* W3t     = (ushort*)alloc((size_t)48 * 256 * 2);
    int2*  pairs    = (int2*) alloc((size_t)NEDGES * 8);
    char*  R1       = alloc((size_t)NNODES * 256 * 2);   // 51.2 MB
    char*  R2       = alloc((size_t)NNODES * 256 * 2);   // 51.2 MB
    char*  R3       = alloc((size_t)NNODES * 256 * 2);   // 51.2 MB

    // R1: xbf16 [0,25.6M) + P_bf [25.6M,51.2M); after gmm128 both dead -> t3_bf
    ushort* xbf16 = (ushort*)R1;
    ushort* P_bf  = (ushort*)R1 + (size_t)NNODES * 128;
    ushort* t3_bf = (ushort*)R1;
    // R2: h1_bf (written by gmm128, read by gmm256); then h2_bf (aggh256 out)
    ushort* h1_bf = (ushort*)R2;
    ushort* h2_bf = (ushort*)R2;
    // R3: t_bf (gmm256 out; distinct from h1_bf, blocks re-read A rows)
    ushort* t_bf  = (ushort*)R3;

    float* sums1 = stats;        float* scsh1 = stats + 512;
    float* sums2 = stats + 1024; float* scsh2 = stats + 1536;

    hipMemsetAsync(cnt, 0, (size_t)NNODES * 4, stream);
    hipMemsetAsync(stats, 0, (size_t)2048 * 4, stream);

    // CSR build
    k_hist<<<NEDGES / 512, 256, 0, stream>>>(edst, cnt);
    k_deg<<<NCH, 256, 0, stream>>>(cnt, dinv, chunksums);
    k_scan1<<<1, 512, 0, stream>>>(chunksums, rowstart);
    k_scan2<<<NCH, 256, 0, stream>>>(cnt, chunksums, rowstart, cursor);
    k_scatter<<<NEDGES / 256, 256, 0, stream>>>(esrc, edst, dinv, cursor, pairs);

    // converts
    k_wconv3<<<560, 256, 0, stream>>>(W1, W2, W3, W1t, W2t, W3t);
    k_xtobf16<<<NNODES * 128 / 4 / 256, 256, 0, stream>>>(x, xbf16);

    dim3 ggrid((NNODES + 127) / 128, 2);

    // Layer 1: P = Agg(x); h1 = P@W1 (stats fused); scsh1
    k_aggh<128, 8><<<NNODES / 4, 256, 0, stream>>>(xbf16, P_bf, pairs, rowstart, dinv);
    k_gmm<128, false, true><<<ggrid, 256, 0, stream>>>(P_bf, W1t, nullptr, h1_bf, sums1);
    k_bnfin<<<1, 256, 0, stream>>>(sums1, g1, be1, scsh1);

    // Layer 2: t = relu(bn(h1))@W2; h2 = Agg(t); stats(h2); scsh2
    k_gmm<256, true, false><<<ggrid, 256, 0, stream>>>(h1_bf, W2t, scsh1, t_bf, nullptr);
    k_aggh<256, 8><<<NNODES / 4, 256, 0, stream>>>(t_bf, h2_bf, pairs, rowstart, dinv);
    k_bnstats_bf<<<NCH, 256, 0, stream>>>((const uint*)h2_bf, sums2);
    k_bnfin<<<1, 256, 0, stream>>>(sums2, g2, be2, scsh2);

    // Layer 3: t3 = relu(bn(h2))@W3 (MFMA, fused BN); out = log_softmax(Agg(t3)+b3) (fused)
    k_gmm3m<<<(NNODES + 127) / 128, 256, 0, stream>>>(h2_bf, W3t, scsh2, t3_bf);
    k_agg40lsm<<<NNODES / 8, 256, 0, stream>>>(t3_bf, out, pairs, rowstart, dinv, b3);
}